// Round 3
// baseline (599.400 us; speedup 1.0000x reference)
//
#include <hip/hip_runtime.h>
#include <hip/hip_bf16.h>
#include <stdint.h>

// DeformableBlock: offset-conv -> deformable conv (bf16 MFMA GEMM) -> GroupNorm+ReLU
// B=4, CIN=COUT=256, H=W=64, K=3x3=9 taps, GN groups=32.

typedef unsigned short u16;
typedef __bf16 bf16x8 __attribute__((ext_vector_type(8)));
typedef float f32x4_t __attribute__((ext_vector_type(4)));

#define HW 4096

__device__ __forceinline__ uint32_t f32_to_bf16_rne(float f) {
  uint32_t u = __builtin_bit_cast(uint32_t, f);
  return (u + 0x7FFFu + ((u >> 16) & 1u)) >> 16;
}

// ---------------- Kernel T: x NCHW -> NHWC (f32) ----------------
__global__ __launch_bounds__(256) void k_transpose(const float* __restrict__ x,
                                                   float* __restrict__ xt) {
  __shared__ float tile[32][33];
  int b = blockIdx.z;
  int c0 = blockIdx.y * 32;
  int p0 = blockIdx.x * 32;
  int tx = threadIdx.x, ty = threadIdx.y;  // 32 x 8
#pragma unroll
  for (int j = 0; j < 32; j += 8)
    tile[ty + j][tx] = x[(b * 256 + c0 + ty + j) * HW + p0 + tx];
  __syncthreads();
#pragma unroll
  for (int j = 0; j < 32; j += 8)
    xt[(b * HW + p0 + ty + j) * 256 + c0 + tx] = tile[tx][ty + j];
}

// ---------------- Kernel W1: deform_w -> bf16 A-tile layout ----------------
// warr[kc][mt][g][m][kk], kc=0..35 (tap=kc>>2, cinblk=(kc&3)*64), g=0..7, m=0..127, kk=0..7
__global__ __launch_bounds__(256) void k_prep_w(const float* __restrict__ wsrc,
                                                u16* __restrict__ warr) {
  int e = blockIdx.x * 256 + threadIdx.x;
  int kk = e & 7, m = (e >> 3) & 127, g = (e >> 10) & 7, mt = (e >> 13) & 1, kc = e >> 14;
  int cout = mt * 128 + m;
  int cin = (kc & 3) * 64 + g * 8 + kk;
  int tap = kc >> 2;
  float v = wsrc[cout * 2304 + cin * 9 + tap];
  warr[e] = (u16)f32_to_bf16_rne(v);
}

// ---------------- Kernel W2: offset_w -> owt[k][oc][c] f32 ----------------
__global__ __launch_bounds__(256) void k_prep_ow(const float* __restrict__ ow,
                                                 float* __restrict__ owt) {
  int e = blockIdx.x * 256 + threadIdx.x;  // (k*18+oc)*256 + c
  int c = e & 255;
  int oc = (e >> 8) % 18;
  int k = e / (18 * 256);
  owt[e] = ow[oc * 2304 + c * 9 + k];
}

// ---------------- Kernel A: offset conv (f32) + bilinear metadata ----------------
// One wave per pixel. Lane covers 4 channels. Butterfly all-reduce for 18 outputs.
__global__ __launch_bounds__(256) void k_offset_meta(
    const float* __restrict__ xt, const float* __restrict__ owt,
    const float* __restrict__ ob, int4* __restrict__ midx, float4* __restrict__ mwt) {
  int lane = threadIdx.x & 63;
  int pid = blockIdx.x * 4 + (threadIdx.x >> 6);
  int b = pid >> 12, p = pid & 4095;
  int y = p >> 6, xx = p & 63;
  float acc[18];
#pragma unroll
  for (int i = 0; i < 18; i++) acc[i] = 0.f;
  int cq = lane * 4;
#pragma unroll
  for (int k = 0; k < 9; k++) {
    int ky = k / 3, kx = k % 3;
    int yy = y - 1 + ky, xx2 = xx - 1 + kx;
    float4 xv = make_float4(0.f, 0.f, 0.f, 0.f);
    if (yy >= 0 && yy < 64 && xx2 >= 0 && xx2 < 64)
      xv = *(const float4*)&xt[(b * HW + yy * 64 + xx2) * 256 + cq];
#pragma unroll
    for (int oc = 0; oc < 18; oc++) {
      float4 w4 = *(const float4*)&owt[((k * 18 + oc) << 8) + cq];
      acc[oc] += xv.x * w4.x + xv.y * w4.y + xv.z * w4.z + xv.w * w4.w;
    }
  }
#pragma unroll
  for (int oc = 0; oc < 18; oc++) {
    float v = acc[oc];
#pragma unroll
    for (int m = 1; m < 64; m <<= 1) v += __shfl_xor(v, m);
    acc[oc] = v;
  }
  if (lane < 9) {
    int k = lane;
    int ky = k / 3, kx = k % 3;
    float dy = acc[2 * k] + ob[2 * k];
    float dx = acc[2 * k + 1] + ob[2 * k + 1];
    float py = (float)(y - 1 + ky) + dy;
    float px = (float)(xx - 1 + kx) + dx;
    float y0f = floorf(py), x0f = floorf(px);
    float ty = py - y0f, tx = px - x0f;
    int y0 = (int)y0f, x0 = (int)x0f;
    int y1 = y0 + 1, x1 = x0 + 1;
    float wy0 = 1.f - ty, wy1 = ty, wx0 = 1.f - tx, wx1 = tx;
    bool vy0 = (y0 >= 0) && (y0 < 64), vy1 = (y1 >= 0) && (y1 < 64);
    bool vx0 = (x0 >= 0) && (x0 < 64), vx1 = (x1 >= 0) && (x1 < 64);
    int cy0 = min(max(y0, 0), 63), cy1 = min(max(y1, 0), 63);
    int cx0 = min(max(x0, 0), 63), cx1 = min(max(x1, 0), 63);
    int base = b * HW;
    int4 ci;
    ci.x = (base + cy0 * 64 + cx0) * 256;
    ci.y = (base + cy0 * 64 + cx1) * 256;
    ci.z = (base + cy1 * 64 + cx0) * 256;
    ci.w = (base + cy1 * 64 + cx1) * 256;
    float4 mw;
    mw.x = wy0 * wx0 * ((vy0 && vx0) ? 1.f : 0.f);
    mw.y = wy0 * wx1 * ((vy0 && vx1) ? 1.f : 0.f);
    mw.z = wy1 * wx0 * ((vy1 && vx0) ? 1.f : 0.f);
    mw.w = wy1 * wx1 * ((vy1 && vx1) ? 1.f : 0.f);
    int mi = (b * 9 + k) * HW + p;
    midx[mi] = ci;
    mwt[mi] = mw;
  }
}

// ---------------- Kernel G: deformable conv as bf16 MFMA GEMM ----------------
// M=cout (tile 128, 2 tiles), N=pixels (tile 128), K=2304 (36 chunks of 64).
// A = weights (pre-arranged bf16), B = bilinear-sampled x (built in staging).
// D written directly to NCHW f32 (pre-GN) in d_out.
__global__ __launch_bounds__(256) void k_gemm(
    const float* __restrict__ xt, const u16* __restrict__ warr,
    const int4* __restrict__ midx, const float4* __restrict__ mwt,
    float* __restrict__ out) {
  __shared__ u16 a_t[8 * 1024];  // [g][m=128][kk=8]
  __shared__ u16 b_t[8 * 1040];  // [g][px=128][kk=8] + 16-u16 pad per g (bank swizzle)
  int tid = threadIdx.x;
  int lane = tid & 63;
  int wave = tid >> 6;
  int wm = wave & 1, wn = wave >> 1;
  int bx = blockIdx.x;
  int mt = blockIdx.y;
  int b = bx >> 5, pt = bx & 31;
  int p0 = pt * 128;

  f32x4_t acc[4][4] = {};

  for (int kc = 0; kc < 36; kc++) {
    int tap = kc >> 2;
    int c0 = (kc & 3) * 64;
    // --- A stage: copy 16KB bf16 chunk (register path) ---
    {
      const uint4* src = (const uint4*)(warr + (kc * 2 + mt) * 8192);
#pragma unroll
      for (int i = 0; i < 4; i++) {
        uint4 v = src[tid + i * 256];
        *(uint4*)&a_t[(tid + i * 256) * 8] = v;
      }
    }
    // --- B stage: bilinear blend 128px x 64ch, write bf16 to LDS ---
    int q = tid & 15;            // channel quad (q-fastest across lanes -> coalesced loads)
    int pxb = tid >> 4;          // 0..15
    int e = c0 + q * 4;
#pragma unroll
    for (int i = 0; i < 8; i++) {
      int px = i * 16 + pxb;
      int mi = (b * 9 + tap) * HW + p0 + px;
      int4 ci = midx[mi];
      float4 mw = mwt[mi];
      const float4* x4 = (const float4*)xt;
      float4 v0 = x4[(ci.x + e) >> 2];
      float4 v1 = x4[(ci.y + e) >> 2];
      float4 v2 = x4[(ci.z + e) >> 2];
      float4 v3 = x4[(ci.w + e) >> 2];
      float rx = mw.x * v0.x + mw.y * v1.x + mw.z * v2.x + mw.w * v3.x;
      float ry = mw.x * v0.y + mw.y * v1.y + mw.z * v2.y + mw.w * v3.y;
      float rz = mw.x * v0.z + mw.y * v1.z + mw.z * v2.z + mw.w * v3.z;
      float rw = mw.x * v0.w + mw.y * v1.w + mw.z * v2.w + mw.w * v3.w;
      uint2 u;
      u.x = f32_to_bf16_rne(rx) | (f32_to_bf16_rne(ry) << 16);
      u.y = f32_to_bf16_rne(rz) | (f32_to_bf16_rne(rw) << 16);
      *(uint2*)&b_t[(q >> 1) * 1040 + px * 8 + (q & 1) * 4] = u;
    }
    __syncthreads();
#pragma unroll
    for (int ks = 0; ks < 2; ks++) {
      int g = ks * 4 + (lane >> 4);
      bf16x8 af[4], bfr[4];
#pragma unroll
      for (int im = 0; im < 4; im++)
        af[im] = *(bf16x8*)&a_t[g * 1024 + (wm * 64 + im * 16 + (lane & 15)) * 8];
#pragma unroll
      for (int in = 0; in < 4; in++)
        bfr[in] = *(bf16x8*)&b_t[g * 1040 + (wn * 64 + in * 16 + (lane & 15)) * 8];
#pragma unroll
      for (int im = 0; im < 4; im++)
#pragma unroll
        for (int in = 0; in < 4; in++)
          acc[im][in] = __builtin_amdgcn_mfma_f32_16x16x32_bf16(af[im], bfr[in], acc[im][in], 0, 0, 0);
    }
    __syncthreads();
  }
  // --- epilogue: D frag col=lane&15 (pixel), row=(lane>>4)*4+r (cout) -> NCHW ---
  int rq = lane >> 4;
#pragma unroll
  for (int im = 0; im < 4; im++) {
#pragma unroll
    for (int in = 0; in < 4; in++) {
      int n = p0 + wn * 64 + in * 16 + (lane & 15);
#pragma unroll
      for (int r = 0; r < 4; r++) {
        int m = mt * 128 + wm * 64 + im * 16 + rq * 4 + r;
        out[(b * 256 + m) * HW + n] = acc[im][in][r];
      }
    }
  }
}

// ---------------- Kernel R: GroupNorm stats (per b,group) ----------------
__global__ __launch_bounds__(256) void k_gn_reduce(const float* __restrict__ out,
                                                   float2* __restrict__ stats) {
  int bg = blockIdx.x;  // b*32+g
  const float4* base = (const float4*)(out + (size_t)bg * 32768);
  int tid = threadIdx.x;
  float s = 0.f, ss = 0.f;
#pragma unroll
  for (int i = 0; i < 32; i++) {
    float4 v = base[tid + i * 256];
    s += v.x + v.y + v.z + v.w;
    ss += v.x * v.x + v.y * v.y + v.z * v.z + v.w * v.w;
  }
#pragma unroll
  for (int m = 1; m < 64; m <<= 1) {
    s += __shfl_xor(s, m);
    ss += __shfl_xor(ss, m);
  }
  __shared__ float ls[4], lss[4];
  int wv = tid >> 6, lane = tid & 63;
  if (lane == 0) { ls[wv] = s; lss[wv] = ss; }
  __syncthreads();
  if (tid == 0) {
    float S = ls[0] + ls[1] + ls[2] + ls[3];
    float SS = lss[0] + lss[1] + lss[2] + lss[3];
    float mu = S / 32768.f;
    float var = SS / 32768.f - mu * mu;
    stats[bg] = make_float2(mu, rsqrtf(var + 1e-5f));
  }
}

// ---------------- Kernel N: normalize + ReLU in place ----------------
// One thread per float4; out has 4*256*4096 floats = 1,048,576 float4 -> 4096 blocks.
__global__ __launch_bounds__(256) void k_gn_apply(float* __restrict__ out,
                                                  const float2* __restrict__ stats,
                                                  const float* __restrict__ gamma,
                                                  const float* __restrict__ beta) {
  int gid = blockIdx.x * 256 + threadIdx.x;  // float4 index, < 1048576
  int c = (gid >> 10) & 255;
  int bb = gid >> 18;
  float2 st = stats[bb * 32 + (c >> 3)];
  float ga = gamma[c] * st.y;
  float be = beta[c] - st.x * ga;
  float4 v = ((const float4*)out)[gid];
  v.x = fmaxf(v.x * ga + be, 0.f);
  v.y = fmaxf(v.y * ga + be, 0.f);
  v.z = fmaxf(v.z * ga + be, 0.f);
  v.w = fmaxf(v.w * ga + be, 0.f);
  ((float4*)out)[gid] = v;
}

extern "C" void kernel_launch(void* const* d_in, const int* in_sizes, int n_in,
                              void* d_out, int out_size, void* d_ws, size_t ws_size,
                              hipStream_t stream) {
  const float* x = (const float*)d_in[0];
  const float* offset_w = (const float*)d_in[1];
  const float* offset_b = (const float*)d_in[2];
  const float* deform_w = (const float*)d_in[3];
  const float* gn_gamma = (const float*)d_in[4];
  const float* gn_beta = (const float*)d_in[5];
  float* out = (float*)d_out;
  char* ws = (char*)d_ws;

  float* xt = (float*)ws;                                    // 16,777,216 B
  int4* midx = (int4*)(ws + 16777216);                       //  2,359,296 B
  float4* mwt = (float4*)(ws + 16777216 + 2359296);          //  2,359,296 B
  u16* warr = (u16*)(ws + 16777216 + 2 * 2359296);           //  1,179,648 B
  float* owt = (float*)(ws + 16777216 + 2 * 2359296 + 1179648);  // 165,888 B
  float2* stats = (float2*)(ws + 16777216 + 2 * 2359296 + 1179648 + 165888);

  k_transpose<<<dim3(128, 8, 4), dim3(32, 8), 0, stream>>>(x, xt);
  k_prep_w<<<dim3(2304), dim3(256), 0, stream>>>(deform_w, warr);
  k_prep_ow<<<dim3(162), dim3(256), 0, stream>>>(offset_w, owt);
  k_offset_meta<<<dim3(4096), dim3(256), 0, stream>>>(xt, owt, offset_b, midx, mwt);
  k_gemm<<<dim3(128, 2), dim3(256), 0, stream>>>(xt, warr, midx, mwt, out);
  k_gn_reduce<<<dim3(128), dim3(256), 0, stream>>>(out, stats);
  k_gn_apply<<<dim3(4096), dim3(256), 0, stream>>>(out, stats, gn_gamma, gn_beta);
}

// Round 4
// 577.518 us; speedup vs baseline: 1.0379x; 1.0379x over previous
//
#include <hip/hip_runtime.h>
#include <hip/hip_bf16.h>
#include <stdint.h>

// DeformableBlock: offset-conv -> deformable conv (bf16 MFMA GEMM) -> GroupNorm+ReLU
// B=4, CIN=COUT=256, H=W=64, K=3x3=9 taps, GN groups=32.

typedef unsigned short u16;
typedef __bf16 bf16x8 __attribute__((ext_vector_type(8)));
typedef float f32x4_t __attribute__((ext_vector_type(4)));

#define HW 4096

__device__ __forceinline__ uint32_t f32_to_bf16_rne(float f) {
  uint32_t u = __builtin_bit_cast(uint32_t, f);
  return (u + 0x7FFFu + ((u >> 16) & 1u)) >> 16;
}

// ---------------- Kernel T: x NCHW -> NHWC (f32) ----------------
__global__ __launch_bounds__(256) void k_transpose(const float* __restrict__ x,
                                                   float* __restrict__ xt) {
  __shared__ float tile[32][33];
  int b = blockIdx.z;
  int c0 = blockIdx.y * 32;
  int p0 = blockIdx.x * 32;
  int tx = threadIdx.x, ty = threadIdx.y;  // 32 x 8
#pragma unroll
  for (int j = 0; j < 32; j += 8)
    tile[ty + j][tx] = x[(b * 256 + c0 + ty + j) * HW + p0 + tx];
  __syncthreads();
#pragma unroll
  for (int j = 0; j < 32; j += 8)
    xt[(b * HW + p0 + ty + j) * 256 + c0 + tx] = tile[tx][ty + j];
}

// ---------------- Kernel W1: deform_w -> bf16 A-tile layout ----------------
// warr[kc][mt][g][m][kk], kc=0..35 (tap=kc>>2, cinblk=(kc&3)*64), g=0..7, m=0..127, kk=0..7
__global__ __launch_bounds__(256) void k_prep_w(const float* __restrict__ wsrc,
                                                u16* __restrict__ warr) {
  int e = blockIdx.x * 256 + threadIdx.x;
  int kk = e & 7, m = (e >> 3) & 127, g = (e >> 10) & 7, mt = (e >> 13) & 1, kc = e >> 14;
  int cout = mt * 128 + m;
  int cin = (kc & 3) * 64 + g * 8 + kk;
  int tap = kc >> 2;
  float v = wsrc[cout * 2304 + cin * 9 + tap];
  warr[e] = (u16)f32_to_bf16_rne(v);
}

// ---------------- Kernel W2: offset_w -> owt[k][oc][c] f32 ----------------
__global__ __launch_bounds__(256) void k_prep_ow(const float* __restrict__ ow,
                                                 float* __restrict__ owt) {
  int e = blockIdx.x * 256 + threadIdx.x;  // (k*18+oc)*256 + c
  int c = e & 255;
  int oc = (e >> 8) % 18;
  int k = e / (18 * 256);
  owt[e] = ow[oc * 2304 + c * 9 + k];
}

// ---------------- Kernel A: offset conv (f32) + bilinear metadata ----------------
// One wave per pixel. Lane covers 4 channels. Butterfly all-reduce for 18 outputs.
// NOTE: no dynamic indexing into acc[] anywhere -> stays in VGPRs (round-3 fix:
// acc[2*k] with k=lane forced the whole array to scratch -> 496MB scratch traffic).
__global__ __launch_bounds__(256) void k_offset_meta(
    const float* __restrict__ xt, const float* __restrict__ owt,
    const float* __restrict__ ob, int4* __restrict__ midx, float4* __restrict__ mwt) {
  int lane = threadIdx.x & 63;
  int pid = blockIdx.x * 4 + (threadIdx.x >> 6);
  int b = pid >> 12, p = pid & 4095;
  int y = p >> 6, xx = p & 63;
  float acc[18];
#pragma unroll
  for (int i = 0; i < 18; i++) acc[i] = 0.f;
  int cq = lane * 4;
#pragma unroll
  for (int k = 0; k < 9; k++) {
    int ky = k / 3, kx = k % 3;
    int yy = y - 1 + ky, xx2 = xx - 1 + kx;
    float4 xv = make_float4(0.f, 0.f, 0.f, 0.f);
    if (yy >= 0 && yy < 64 && xx2 >= 0 && xx2 < 64)
      xv = *(const float4*)&xt[(b * HW + yy * 64 + xx2) * 256 + cq];
#pragma unroll
    for (int oc = 0; oc < 18; oc++) {
      float4 w4 = *(const float4*)&owt[((k * 18 + oc) << 8) + cq];
      acc[oc] += xv.x * w4.x + xv.y * w4.y + xv.z * w4.z + xv.w * w4.w;
    }
  }
#pragma unroll
  for (int oc = 0; oc < 18; oc++) {
    float v = acc[oc];
#pragma unroll
    for (int m = 1; m < 64; m <<= 1) v += __shfl_xor(v, m);
    acc[oc] = v;
  }
  // lane l < 9 handles tap l: select acc[2l], acc[2l+1] WITHOUT dynamic indexing
  float dy = 0.f, dx = 0.f;
#pragma unroll
  for (int t = 0; t < 9; t++) {
    if (lane == t) { dy = acc[2 * t]; dx = acc[2 * t + 1]; }
  }
  if (lane < 9) {
    int k = lane;
    int ky = k / 3, kx = k % 3;
    dy += ob[2 * k];
    dx += ob[2 * k + 1];
    float py = (float)(y - 1 + ky) + dy;
    float px = (float)(xx - 1 + kx) + dx;
    float y0f = floorf(py), x0f = floorf(px);
    float ty = py - y0f, tx = px - x0f;
    int y0 = (int)y0f, x0 = (int)x0f;
    int y1 = y0 + 1, x1 = x0 + 1;
    float wy0 = 1.f - ty, wy1 = ty, wx0 = 1.f - tx, wx1 = tx;
    bool vy0 = (y0 >= 0) && (y0 < 64), vy1 = (y1 >= 0) && (y1 < 64);
    bool vx0 = (x0 >= 0) && (x0 < 64), vx1 = (x1 >= 0) && (x1 < 64);
    int cy0 = min(max(y0, 0), 63), cy1 = min(max(y1, 0), 63);
    int cx0 = min(max(x0, 0), 63), cx1 = min(max(x1, 0), 63);
    int base = b * HW;
    int4 ci;
    ci.x = (base + cy0 * 64 + cx0) * 256;
    ci.y = (base + cy0 * 64 + cx1) * 256;
    ci.z = (base + cy1 * 64 + cx0) * 256;
    ci.w = (base + cy1 * 64 + cx1) * 256;
    float4 mw;
    mw.x = wy0 * wx0 * ((vy0 && vx0) ? 1.f : 0.f);
    mw.y = wy0 * wx1 * ((vy0 && vx1) ? 1.f : 0.f);
    mw.z = wy1 * wx0 * ((vy1 && vx0) ? 1.f : 0.f);
    mw.w = wy1 * wx1 * ((vy1 && vx1) ? 1.f : 0.f);
    int mi = (b * 9 + k) * HW + p;
    midx[mi] = ci;
    mwt[mi] = mw;
  }
}

// ---------------- Kernel G: deformable conv as bf16 MFMA GEMM ----------------
// M=cout (tile 128, 2 tiles), N=pixels (tile 128), K=2304 (36 chunks of 64).
// A = weights (pre-arranged bf16), B = bilinear-sampled x (built in staging).
// D written directly to NCHW f32 (pre-GN) in d_out.
__global__ __launch_bounds__(256) void k_gemm(
    const float* __restrict__ xt, const u16* __restrict__ warr,
    const int4* __restrict__ midx, const float4* __restrict__ mwt,
    float* __restrict__ out) {
  __shared__ u16 a_t[8 * 1024];  // [g][m=128][kk=8]
  __shared__ u16 b_t[8 * 1040];  // [g][px=128][kk=8] + 16-u16 pad per g (bank swizzle)
  int tid = threadIdx.x;
  int lane = tid & 63;
  int wave = tid >> 6;
  int wm = wave & 1, wn = wave >> 1;
  int bx = blockIdx.x;
  int mt = blockIdx.y;
  int b = bx >> 5, pt = bx & 31;
  int p0 = pt * 128;

  f32x4_t acc[4][4] = {};

  for (int kc = 0; kc < 36; kc++) {
    int tap = kc >> 2;
    int c0 = (kc & 3) * 64;
    // --- A stage: copy 16KB bf16 chunk (register path) ---
    {
      const uint4* src = (const uint4*)(warr + (kc * 2 + mt) * 8192);
#pragma unroll
      for (int i = 0; i < 4; i++) {
        uint4 v = src[tid + i * 256];
        *(uint4*)&a_t[(tid + i * 256) * 8] = v;
      }
    }
    // --- B stage: bilinear blend 128px x 64ch, write bf16 to LDS ---
    int q = tid & 15;            // channel quad (q-fastest across lanes -> coalesced loads)
    int pxb = tid >> 4;          // 0..15
    int e = c0 + q * 4;
#pragma unroll
    for (int i = 0; i < 8; i++) {
      int px = i * 16 + pxb;
      int mi = (b * 9 + tap) * HW + p0 + px;
      int4 ci = midx[mi];
      float4 mw = mwt[mi];
      const float4* x4 = (const float4*)xt;
      float4 v0 = x4[(ci.x + e) >> 2];
      float4 v1 = x4[(ci.y + e) >> 2];
      float4 v2 = x4[(ci.z + e) >> 2];
      float4 v3 = x4[(ci.w + e) >> 2];
      float rx = mw.x * v0.x + mw.y * v1.x + mw.z * v2.x + mw.w * v3.x;
      float ry = mw.x * v0.y + mw.y * v1.y + mw.z * v2.y + mw.w * v3.y;
      float rz = mw.x * v0.z + mw.y * v1.z + mw.z * v2.z + mw.w * v3.z;
      float rw = mw.x * v0.w + mw.y * v1.w + mw.z * v2.w + mw.w * v3.w;
      uint2 u;
      u.x = f32_to_bf16_rne(rx) | (f32_to_bf16_rne(ry) << 16);
      u.y = f32_to_bf16_rne(rz) | (f32_to_bf16_rne(rw) << 16);
      *(uint2*)&b_t[(q >> 1) * 1040 + px * 8 + (q & 1) * 4] = u;
    }
    __syncthreads();
#pragma unroll
    for (int ks = 0; ks < 2; ks++) {
      int g = ks * 4 + (lane >> 4);
      bf16x8 af[4], bfr[4];
#pragma unroll
      for (int im = 0; im < 4; im++)
        af[im] = *(bf16x8*)&a_t[g * 1024 + (wm * 64 + im * 16 + (lane & 15)) * 8];
#pragma unroll
      for (int in = 0; in < 4; in++)
        bfr[in] = *(bf16x8*)&b_t[g * 1040 + (wn * 64 + in * 16 + (lane & 15)) * 8];
#pragma unroll
      for (int im = 0; im < 4; im++)
#pragma unroll
        for (int in = 0; in < 4; in++)
          acc[im][in] = __builtin_amdgcn_mfma_f32_16x16x32_bf16(af[im], bfr[in], acc[im][in], 0, 0, 0);
    }
    __syncthreads();
  }
  // --- epilogue: D frag col=lane&15 (pixel), row=(lane>>4)*4+r (cout) -> NCHW ---
  int rq = lane >> 4;
#pragma unroll
  for (int im = 0; im < 4; im++) {
#pragma unroll
    for (int in = 0; in < 4; in++) {
      int n = p0 + wn * 64 + in * 16 + (lane & 15);
#pragma unroll
      for (int r = 0; r < 4; r++) {
        int m = mt * 128 + wm * 64 + im * 16 + rq * 4 + r;
        out[(b * 256 + m) * HW + n] = acc[im][in][r];
      }
    }
  }
}

// ---------------- Kernel R: GroupNorm stats (per b,group) ----------------
__global__ __launch_bounds__(256) void k_gn_reduce(const float* __restrict__ out,
                                                   float2* __restrict__ stats) {
  int bg = blockIdx.x;  // b*32+g
  const float4* base = (const float4*)(out + (size_t)bg * 32768);
  int tid = threadIdx.x;
  float s = 0.f, ss = 0.f;
#pragma unroll
  for (int i = 0; i < 32; i++) {
    float4 v = base[tid + i * 256];
    s += v.x + v.y + v.z + v.w;
    ss += v.x * v.x + v.y * v.y + v.z * v.z + v.w * v.w;
  }
#pragma unroll
  for (int m = 1; m < 64; m <<= 1) {
    s += __shfl_xor(s, m);
    ss += __shfl_xor(ss, m);
  }
  __shared__ float ls[4], lss[4];
  int wv = tid >> 6, lane = tid & 63;
  if (lane == 0) { ls[wv] = s; lss[wv] = ss; }
  __syncthreads();
  if (tid == 0) {
    float S = ls[0] + ls[1] + ls[2] + ls[3];
    float SS = lss[0] + lss[1] + lss[2] + lss[3];
    float mu = S / 32768.f;
    float var = SS / 32768.f - mu * mu;
    stats[bg] = make_float2(mu, rsqrtf(var + 1e-5f));
  }
}

// ---------------- Kernel N: normalize + ReLU in place ----------------
// One thread per float4; out has 4*256*4096 floats = 1,048,576 float4 -> 4096 blocks.
__global__ __launch_bounds__(256) void k_gn_apply(float* __restrict__ out,
                                                  const float2* __restrict__ stats,
                                                  const float* __restrict__ gamma,
                                                  const float* __restrict__ beta) {
  int gid = blockIdx.x * 256 + threadIdx.x;  // float4 index, < 1048576
  int c = (gid >> 10) & 255;
  int bb = gid >> 18;
  float2 st = stats[bb * 32 + (c >> 3)];
  float ga = gamma[c] * st.y;
  float be = beta[c] - st.x * ga;
  float4 v = ((const float4*)out)[gid];
  v.x = fmaxf(v.x * ga + be, 0.f);
  v.y = fmaxf(v.y * ga + be, 0.f);
  v.z = fmaxf(v.z * ga + be, 0.f);
  v.w = fmaxf(v.w * ga + be, 0.f);
  ((float4*)out)[gid] = v;
}

extern "C" void kernel_launch(void* const* d_in, const int* in_sizes, int n_in,
                              void* d_out, int out_size, void* d_ws, size_t ws_size,
                              hipStream_t stream) {
  const float* x = (const float*)d_in[0];
  const float* offset_w = (const float*)d_in[1];
  const float* offset_b = (const float*)d_in[2];
  const float* deform_w = (const float*)d_in[3];
  const float* gn_gamma = (const float*)d_in[4];
  const float* gn_beta = (const float*)d_in[5];
  float* out = (float*)d_out;
  char* ws = (char*)d_ws;

  float* xt = (float*)ws;                                    // 16,777,216 B
  int4* midx = (int4*)(ws + 16777216);                       //  2,359,296 B
  float4* mwt = (float4*)(ws + 16777216 + 2359296);          //  2,359,296 B
  u16* warr = (u16*)(ws + 16777216 + 2 * 2359296);           //  1,179,648 B
  float* owt = (float*)(ws + 16777216 + 2 * 2359296 + 1179648);  // 165,888 B
  float2* stats = (float2*)(ws + 16777216 + 2 * 2359296 + 1179648 + 165888);

  k_transpose<<<dim3(128, 8, 4), dim3(32, 8), 0, stream>>>(x, xt);
  k_prep_w<<<dim3(2304), dim3(256), 0, stream>>>(deform_w, warr);
  k_prep_ow<<<dim3(162), dim3(256), 0, stream>>>(offset_w, owt);
  k_offset_meta<<<dim3(4096), dim3(256), 0, stream>>>(xt, owt, offset_b, midx, mwt);
  k_gemm<<<dim3(128, 2), dim3(256), 0, stream>>>(xt, warr, midx, mwt, out);
  k_gn_reduce<<<dim3(128), dim3(256), 0, stream>>>(out, stats);
  k_gn_apply<<<dim3(4096), dim3(256), 0, stream>>>(out, stats, gn_gamma, gn_beta);
}

// Round 5
// 344.607 us; speedup vs baseline: 1.7394x; 1.6759x over previous
//
#include <hip/hip_runtime.h>
#include <hip/hip_bf16.h>
#include <stdint.h>

// DeformableBlock: offset-conv -> deformable conv (bf16 MFMA GEMM) -> GroupNorm+ReLU
// B=4, CIN=COUT=256, H=W=64, K=3x3=9 taps, GN groups=32.

typedef unsigned short u16;
typedef __bf16 bf16x8 __attribute__((ext_vector_type(8)));
typedef float f32x4_t __attribute__((ext_vector_type(4)));

#define HW 4096

__device__ __forceinline__ uint32_t f32_to_bf16_rne(float f) {
  uint32_t u = __builtin_bit_cast(uint32_t, f);
  return (u + 0x7FFFu + ((u >> 16) & 1u)) >> 16;
}

// ---------------- Kernel T: x NCHW -> NHWC (f32) ----------------
__global__ __launch_bounds__(256) void k_transpose(const float* __restrict__ x,
                                                   float* __restrict__ xt) {
  __shared__ float tile[32][33];
  int b = blockIdx.z;
  int c0 = blockIdx.y * 32;
  int p0 = blockIdx.x * 32;
  int tx = threadIdx.x, ty = threadIdx.y;  // 32 x 8
#pragma unroll
  for (int j = 0; j < 32; j += 8)
    tile[ty + j][tx] = x[(b * 256 + c0 + ty + j) * HW + p0 + tx];
  __syncthreads();
#pragma unroll
  for (int j = 0; j < 32; j += 8)
    xt[(b * HW + p0 + ty + j) * 256 + c0 + tx] = tile[tx][ty + j];
}

// ---------------- Kernel W1: deform_w -> bf16 A-tile layout ----------------
// warr[kc][mt][g][m][kk], kc=0..35 (tap=kc>>2, cinblk=(kc&3)*64), g=0..7, m=0..127, kk=0..7
__global__ __launch_bounds__(256) void k_prep_w(const float* __restrict__ wsrc,
                                                u16* __restrict__ warr) {
  int e = blockIdx.x * 256 + threadIdx.x;
  int kk = e & 7, m = (e >> 3) & 127, g = (e >> 10) & 7, mt = (e >> 13) & 1, kc = e >> 14;
  int cout = mt * 128 + m;
  int cin = (kc & 3) * 64 + g * 8 + kk;
  int tap = kc >> 2;
  float v = wsrc[cout * 2304 + cin * 9 + tap];
  warr[e] = (u16)f32_to_bf16_rne(v);
}

// ---------------- Kernel W2: offset_w -> owt[k][oc][c] f32 ----------------
__global__ __launch_bounds__(256) void k_prep_ow(const float* __restrict__ ow,
                                                 float* __restrict__ owt) {
  int e = blockIdx.x * 256 + threadIdx.x;  // (k*18+oc)*256 + c
  int c = e & 255;
  int oc = (e >> 8) % 18;
  int k = e / (18 * 256);
  owt[e] = ow[oc * 2304 + c * 9 + k];
}

// ---------------- Kernel A: offset conv (f32) + bilinear metadata ----------------
// One wave per pixel. Lane covers 4 channels. Butterfly all-reduce for 18 outputs.
// k-loop kept rolled (#pragma unroll 1): full unroll put 162 float4 loads in
// flight -> VGPR>256 -> acc[18] spilled to scratch (480MB writes, round 3/4).
__global__ __launch_bounds__(256) void k_offset_meta(
    const float* __restrict__ xt, const float* __restrict__ owt,
    const float* __restrict__ ob, int4* __restrict__ midx, float4* __restrict__ mwt) {
  int lane = threadIdx.x & 63;
  int pid = blockIdx.x * 4 + (threadIdx.x >> 6);
  int b = pid >> 12, p = pid & 4095;
  int y = p >> 6, xx = p & 63;
  float acc[18];
#pragma unroll
  for (int i = 0; i < 18; i++) acc[i] = 0.f;
  int cq = lane * 4;
#pragma unroll 1
  for (int k = 0; k < 9; k++) {
    int ky = k / 3, kx = k % 3;
    int yy = y - 1 + ky, xx2 = xx - 1 + kx;
    float4 xv = make_float4(0.f, 0.f, 0.f, 0.f);
    if (yy >= 0 && yy < 64 && xx2 >= 0 && xx2 < 64)
      xv = *(const float4*)&xt[(b * HW + yy * 64 + xx2) * 256 + cq];
#pragma unroll
    for (int oc = 0; oc < 18; oc++) {
      float4 w4 = *(const float4*)&owt[((k * 18 + oc) << 8) + cq];
      acc[oc] += xv.x * w4.x + xv.y * w4.y + xv.z * w4.z + xv.w * w4.w;
    }
  }
#pragma unroll
  for (int oc = 0; oc < 18; oc++) {
    float v = acc[oc];
#pragma unroll
    for (int m = 1; m < 64; m <<= 1) v += __shfl_xor(v, m);
    acc[oc] = v;
  }
  // lane l < 9 handles tap l: select acc[2l], acc[2l+1] without dynamic indexing
  float dy = 0.f, dx = 0.f;
#pragma unroll
  for (int t = 0; t < 9; t++) {
    if (lane == t) { dy = acc[2 * t]; dx = acc[2 * t + 1]; }
  }
  if (lane < 9) {
    int k = lane;
    int ky = k / 3, kx = k % 3;
    dy += ob[2 * k];
    dx += ob[2 * k + 1];
    float py = (float)(y - 1 + ky) + dy;
    float px = (float)(xx - 1 + kx) + dx;
    float y0f = floorf(py), x0f = floorf(px);
    float ty = py - y0f, tx = px - x0f;
    int y0 = (int)y0f, x0 = (int)x0f;
    int y1 = y0 + 1, x1 = x0 + 1;
    float wy0 = 1.f - ty, wy1 = ty, wx0 = 1.f - tx, wx1 = tx;
    bool vy0 = (y0 >= 0) && (y0 < 64), vy1 = (y1 >= 0) && (y1 < 64);
    bool vx0 = (x0 >= 0) && (x0 < 64), vx1 = (x1 >= 0) && (x1 < 64);
    int cy0 = min(max(y0, 0), 63), cy1 = min(max(y1, 0), 63);
    int cx0 = min(max(x0, 0), 63), cx1 = min(max(x1, 0), 63);
    int base = b * HW;
    int4 ci;
    ci.x = (base + cy0 * 64 + cx0) * 256;
    ci.y = (base + cy0 * 64 + cx1) * 256;
    ci.z = (base + cy1 * 64 + cx0) * 256;
    ci.w = (base + cy1 * 64 + cx1) * 256;
    float4 mw;
    mw.x = wy0 * wx0 * ((vy0 && vx0) ? 1.f : 0.f);
    mw.y = wy0 * wx1 * ((vy0 && vx1) ? 1.f : 0.f);
    mw.z = wy1 * wx0 * ((vy1 && vx0) ? 1.f : 0.f);
    mw.w = wy1 * wx1 * ((vy1 && vx1) ? 1.f : 0.f);
    int mi = (b * 9 + k) * HW + p;
    midx[mi] = ci;
    mwt[mi] = mw;
  }
}

// ---------------- Kernel G: deformable conv as bf16 MFMA GEMM ----------------
// M=cout (tile 128, 2 tiles), N=pixels (tile 128), K=2304 (36 chunks of 64).
// A = weights (pre-arranged bf16), B = bilinear-sampled x (built in staging).
// D written directly to NCHW f32 (pre-GN) in d_out.
__global__ __launch_bounds__(256) void k_gemm(
    const float* __restrict__ xt, const u16* __restrict__ warr,
    const int4* __restrict__ midx, const float4* __restrict__ mwt,
    float* __restrict__ out) {
  __shared__ u16 a_t[8 * 1024];  // [g][m=128][kk=8]
  __shared__ u16 b_t[8 * 1040];  // [g][px=128][kk=8] + 16-u16 pad per g (bank swizzle)
  int tid = threadIdx.x;
  int lane = tid & 63;
  int wave = tid >> 6;
  int wm = wave & 1, wn = wave >> 1;
  int bx = blockIdx.x;
  int mt = blockIdx.y;
  int b = bx >> 5, pt = bx & 31;
  int p0 = pt * 128;

  f32x4_t acc[4][4] = {};

  for (int kc = 0; kc < 36; kc++) {
    int tap = kc >> 2;
    int c0 = (kc & 3) * 64;
    // --- A stage: copy 16KB bf16 chunk (register path) ---
    {
      const uint4* src = (const uint4*)(warr + (kc * 2 + mt) * 8192);
#pragma unroll
      for (int i = 0; i < 4; i++) {
        uint4 v = src[tid + i * 256];
        *(uint4*)&a_t[(tid + i * 256) * 8] = v;
      }
    }
    // --- B stage: bilinear blend 128px x 64ch, write bf16 to LDS ---
    int q = tid & 15;            // channel quad (q-fastest across lanes -> coalesced loads)
    int pxb = tid >> 4;          // 0..15
    int e = c0 + q * 4;
#pragma unroll
    for (int i = 0; i < 8; i++) {
      int px = i * 16 + pxb;
      int mi = (b * 9 + tap) * HW + p0 + px;
      int4 ci = midx[mi];
      float4 mw = mwt[mi];
      const float4* x4 = (const float4*)xt;
      float4 v0 = x4[(ci.x + e) >> 2];
      float4 v1 = x4[(ci.y + e) >> 2];
      float4 v2 = x4[(ci.z + e) >> 2];
      float4 v3 = x4[(ci.w + e) >> 2];
      float rx = mw.x * v0.x + mw.y * v1.x + mw.z * v2.x + mw.w * v3.x;
      float ry = mw.x * v0.y + mw.y * v1.y + mw.z * v2.y + mw.w * v3.y;
      float rz = mw.x * v0.z + mw.y * v1.z + mw.z * v2.z + mw.w * v3.z;
      float rw = mw.x * v0.w + mw.y * v1.w + mw.z * v2.w + mw.w * v3.w;
      uint2 u;
      u.x = f32_to_bf16_rne(rx) | (f32_to_bf16_rne(ry) << 16);
      u.y = f32_to_bf16_rne(rz) | (f32_to_bf16_rne(rw) << 16);
      *(uint2*)&b_t[(q >> 1) * 1040 + px * 8 + (q & 1) * 4] = u;
    }
    __syncthreads();
#pragma unroll
    for (int ks = 0; ks < 2; ks++) {
      int g = ks * 4 + (lane >> 4);
      bf16x8 af[4], bfr[4];
#pragma unroll
      for (int im = 0; im < 4; im++)
        af[im] = *(bf16x8*)&a_t[g * 1024 + (wm * 64 + im * 16 + (lane & 15)) * 8];
#pragma unroll
      for (int in = 0; in < 4; in++)
        bfr[in] = *(bf16x8*)&b_t[g * 1040 + (wn * 64 + in * 16 + (lane & 15)) * 8];
#pragma unroll
      for (int im = 0; im < 4; im++)
#pragma unroll
        for (int in = 0; in < 4; in++)
          acc[im][in] = __builtin_amdgcn_mfma_f32_16x16x32_bf16(af[im], bfr[in], acc[im][in], 0, 0, 0);
    }
    __syncthreads();
  }
  // --- epilogue: D frag col=lane&15 (pixel), row=(lane>>4)*4+r (cout) -> NCHW ---
  int rq = lane >> 4;
#pragma unroll
  for (int im = 0; im < 4; im++) {
#pragma unroll
    for (int in = 0; in < 4; in++) {
      int n = p0 + wn * 64 + in * 16 + (lane & 15);
#pragma unroll
      for (int r = 0; r < 4; r++) {
        int m = mt * 128 + wm * 64 + im * 16 + rq * 4 + r;
        out[(b * 256 + m) * HW + n] = acc[im][in][r];
      }
    }
  }
}

// ---------------- Kernel R: GroupNorm stats (per b,group) ----------------
__global__ __launch_bounds__(256) void k_gn_reduce(const float* __restrict__ out,
                                                   float2* __restrict__ stats) {
  int bg = blockIdx.x;  // b*32+g
  const float4* base = (const float4*)(out + (size_t)bg * 32768);
  int tid = threadIdx.x;
  float s = 0.f, ss = 0.f;
#pragma unroll
  for (int i = 0; i < 32; i++) {
    float4 v = base[tid + i * 256];
    s += v.x + v.y + v.z + v.w;
    ss += v.x * v.x + v.y * v.y + v.z * v.z + v.w * v.w;
  }
#pragma unroll
  for (int m = 1; m < 64; m <<= 1) {
    s += __shfl_xor(s, m);
    ss += __shfl_xor(ss, m);
  }
  __shared__ float ls[4], lss[4];
  int wv = tid >> 6, lane = tid & 63;
  if (lane == 0) { ls[wv] = s; lss[wv] = ss; }
  __syncthreads();
  if (tid == 0) {
    float S = ls[0] + ls[1] + ls[2] + ls[3];
    float SS = lss[0] + lss[1] + lss[2] + lss[3];
    float mu = S / 32768.f;
    float var = SS / 32768.f - mu * mu;
    stats[bg] = make_float2(mu, rsqrtf(var + 1e-5f));
  }
}

// ---------------- Kernel N: normalize + ReLU in place ----------------
// One thread per float4; out has 4*256*4096 floats = 1,048,576 float4 -> 4096 blocks.
__global__ __launch_bounds__(256) void k_gn_apply(float* __restrict__ out,
                                                  const float2* __restrict__ stats,
                                                  const float* __restrict__ gamma,
                                                  const float* __restrict__ beta) {
  int gid = blockIdx.x * 256 + threadIdx.x;  // float4 index, < 1048576
  int c = (gid >> 10) & 255;
  int bb = gid >> 18;
  float2 st = stats[bb * 32 + (c >> 3)];
  float ga = gamma[c] * st.y;
  float be = beta[c] - st.x * ga;
  float4 v = ((const float4*)out)[gid];
  v.x = fmaxf(v.x * ga + be, 0.f);
  v.y = fmaxf(v.y * ga + be, 0.f);
  v.z = fmaxf(v.z * ga + be, 0.f);
  v.w = fmaxf(v.w * ga + be, 0.f);
  ((float4*)out)[gid] = v;
}

extern "C" void kernel_launch(void* const* d_in, const int* in_sizes, int n_in,
                              void* d_out, int out_size, void* d_ws, size_t ws_size,
                              hipStream_t stream) {
  const float* x = (const float*)d_in[0];
  const float* offset_w = (const float*)d_in[1];
  const float* offset_b = (const float*)d_in[2];
  const float* deform_w = (const float*)d_in[3];
  const float* gn_gamma = (const float*)d_in[4];
  const float* gn_beta = (const float*)d_in[5];
  float* out = (float*)d_out;
  char* ws = (char*)d_ws;

  float* xt = (float*)ws;                                    // 16,777,216 B
  int4* midx = (int4*)(ws + 16777216);                       //  2,359,296 B
  float4* mwt = (float4*)(ws + 16777216 + 2359296);          //  2,359,296 B
  u16* warr = (u16*)(ws + 16777216 + 2 * 2359296);           //  1,179,648 B
  float* owt = (float*)(ws + 16777216 + 2 * 2359296 + 1179648);  // 165,888 B
  float2* stats = (float2*)(ws + 16777216 + 2 * 2359296 + 1179648 + 165888);

  k_transpose<<<dim3(128, 8, 4), dim3(32, 8), 0, stream>>>(x, xt);
  k_prep_w<<<dim3(2304), dim3(256), 0, stream>>>(deform_w, warr);
  k_prep_ow<<<dim3(162), dim3(256), 0, stream>>>(offset_w, owt);
  k_offset_meta<<<dim3(4096), dim3(256), 0, stream>>>(xt, owt, offset_b, midx, mwt);
  k_gemm<<<dim3(128, 2), dim3(256), 0, stream>>>(xt, warr, midx, mwt, out);
  k_gn_reduce<<<dim3(128), dim3(256), 0, stream>>>(out, stats);
  k_gn_apply<<<dim3(4096), dim3(256), 0, stream>>>(out, stats, gn_gamma, gn_beta);
}

// Round 6
// 284.327 us; speedup vs baseline: 2.1081x; 1.2120x over previous
//
#include <hip/hip_runtime.h>
#include <hip/hip_bf16.h>
#include <stdint.h>

// DeformableBlock: offset-conv -> deformable conv (bf16 MFMA GEMM) -> GroupNorm+ReLU
// B=4, CIN=COUT=256, H=W=64, K=3x3=9 taps, GN groups=32.
// xt kept in bf16 NHWC (halves gather bytes; B operand is bf16 in the GEMM anyway).

typedef unsigned short u16;
typedef __bf16 bf16x8 __attribute__((ext_vector_type(8)));
typedef float f32x4_t __attribute__((ext_vector_type(4)));

#define HW 4096

__device__ __forceinline__ uint32_t f32_to_bf16_rne(float f) {
  uint32_t u = __builtin_bit_cast(uint32_t, f);
  return (u + 0x7FFFu + ((u >> 16) & 1u)) >> 16;
}
__device__ __forceinline__ float bf_lo(uint32_t u) {  // low u16 as f32
  return __builtin_bit_cast(float, u << 16);
}
__device__ __forceinline__ float bf_hi(uint32_t u) {  // high u16 as f32
  return __builtin_bit_cast(float, u & 0xFFFF0000u);
}

// ---------------- Kernel T: x NCHW f32 -> NHWC bf16 ----------------
__global__ __launch_bounds__(256) void k_transpose(const float* __restrict__ x,
                                                   u16* __restrict__ xt) {
  __shared__ float tile[32][33];
  int b = blockIdx.z;
  int c0 = blockIdx.y * 32;
  int p0 = blockIdx.x * 32;
  int tx = threadIdx.x, ty = threadIdx.y;  // 32 x 8
#pragma unroll
  for (int j = 0; j < 32; j += 8)
    tile[ty + j][tx] = x[(b * 256 + c0 + ty + j) * HW + p0 + tx];
  __syncthreads();
  int wid = ty * 32 + tx;
  int cp = wid & 15;   // channel pair -> c = c0 + 2*cp
  int pr = wid >> 4;   // 0..15
#pragma unroll
  for (int j = 0; j < 2; j++) {
    int p = pr + j * 16;
    uint32_t lo = f32_to_bf16_rne(tile[cp * 2][p]);
    uint32_t hi = f32_to_bf16_rne(tile[cp * 2 + 1][p]);
    *(uint32_t*)&xt[(b * HW + p0 + p) * 256 + c0 + cp * 2] = lo | (hi << 16);
  }
}

// ---------------- Kernel W1: deform_w -> bf16 A-tile layout ----------------
// warr[kc][mt][g][m][kk], kc=0..35 (tap=kc>>2, cinblk=(kc&3)*64), g=0..7, m=0..127, kk=0..7
__global__ __launch_bounds__(256) void k_prep_w(const float* __restrict__ wsrc,
                                                u16* __restrict__ warr) {
  int e = blockIdx.x * 256 + threadIdx.x;
  int kk = e & 7, m = (e >> 3) & 127, g = (e >> 10) & 7, mt = (e >> 13) & 1, kc = e >> 14;
  int cout = mt * 128 + m;
  int cin = (kc & 3) * 64 + g * 8 + kk;
  int tap = kc >> 2;
  float v = wsrc[cout * 2304 + cin * 9 + tap];
  warr[e] = (u16)f32_to_bf16_rne(v);
}

// ---------------- Kernel W2: offset_w -> owt[k][oc][c] f32 ----------------
__global__ __launch_bounds__(256) void k_prep_ow(const float* __restrict__ ow,
                                                 float* __restrict__ owt) {
  int e = blockIdx.x * 256 + threadIdx.x;  // (k*18+oc)*256 + c
  int c = e & 255;
  int oc = (e >> 8) % 18;
  int k = e / (18 * 256);
  owt[e] = ow[oc * 2304 + c * 9 + k];
}

// ---------------- Kernel A: offset conv + bilinear metadata ----------------
// One wave per pixel; lane covers 4 channels (bf16 loads). k-loop rolled to
// bound VGPR (full unroll spilled acc[18] -> 480MB scratch, rounds 3/4).
__global__ __launch_bounds__(256) void k_offset_meta(
    const u16* __restrict__ xt, const float* __restrict__ owt,
    const float* __restrict__ ob, int4* __restrict__ midx, float4* __restrict__ mwt) {
  int lane = threadIdx.x & 63;
  int pid = blockIdx.x * 4 + (threadIdx.x >> 6);
  int b = pid >> 12, p = pid & 4095;
  int y = p >> 6, xx = p & 63;
  float acc[18];
#pragma unroll
  for (int i = 0; i < 18; i++) acc[i] = 0.f;
  int cq = lane * 4;
#pragma unroll 1
  for (int k = 0; k < 9; k++) {
    int ky = k / 3, kx = k % 3;
    int yy = y - 1 + ky, xx2 = xx - 1 + kx;
    uint2 xv2 = make_uint2(0u, 0u);
    if (yy >= 0 && yy < 64 && xx2 >= 0 && xx2 < 64)
      xv2 = *(const uint2*)&xt[(b * HW + yy * 64 + xx2) * 256 + cq];
    float x0 = bf_lo(xv2.x), x1 = bf_hi(xv2.x);
    float x2 = bf_lo(xv2.y), x3 = bf_hi(xv2.y);
#pragma unroll
    for (int oc = 0; oc < 18; oc++) {
      float4 w4 = *(const float4*)&owt[((k * 18 + oc) << 8) + cq];
      acc[oc] += x0 * w4.x + x1 * w4.y + x2 * w4.z + x3 * w4.w;
    }
  }
#pragma unroll
  for (int oc = 0; oc < 18; oc++) {
    float v = acc[oc];
#pragma unroll
    for (int m = 1; m < 64; m <<= 1) v += __shfl_xor(v, m);
    acc[oc] = v;
  }
  // lane l < 9 handles tap l: select acc[2l], acc[2l+1] without dynamic indexing
  float dy = 0.f, dx = 0.f;
#pragma unroll
  for (int t = 0; t < 9; t++) {
    if (lane == t) { dy = acc[2 * t]; dx = acc[2 * t + 1]; }
  }
  if (lane < 9) {
    int k = lane;
    int ky = k / 3, kx = k % 3;
    dy += ob[2 * k];
    dx += ob[2 * k + 1];
    float py = (float)(y - 1 + ky) + dy;
    float px = (float)(xx - 1 + kx) + dx;
    float y0f = floorf(py), x0f = floorf(px);
    float ty = py - y0f, tx = px - x0f;
    int y0 = (int)y0f, x0 = (int)x0f;
    int y1 = y0 + 1, x1 = x0 + 1;
    float wy0 = 1.f - ty, wy1 = ty, wx0 = 1.f - tx, wx1 = tx;
    bool vy0 = (y0 >= 0) && (y0 < 64), vy1 = (y1 >= 0) && (y1 < 64);
    bool vx0 = (x0 >= 0) && (x0 < 64), vx1 = (x1 >= 0) && (x1 < 64);
    int cy0 = min(max(y0, 0), 63), cy1 = min(max(y1, 0), 63);
    int cx0 = min(max(x0, 0), 63), cx1 = min(max(x1, 0), 63);
    int base = b * HW;
    int4 ci;
    ci.x = (base + cy0 * 64 + cx0) * 256;
    ci.y = (base + cy0 * 64 + cx1) * 256;
    ci.z = (base + cy1 * 64 + cx0) * 256;
    ci.w = (base + cy1 * 64 + cx1) * 256;
    float4 mw;
    mw.x = wy0 * wx0 * ((vy0 && vx0) ? 1.f : 0.f);
    mw.y = wy0 * wx1 * ((vy0 && vx1) ? 1.f : 0.f);
    mw.z = wy1 * wx0 * ((vy1 && vx0) ? 1.f : 0.f);
    mw.w = wy1 * wx1 * ((vy1 && vx1) ? 1.f : 0.f);
    int mi = (b * 9 + k) * HW + p;
    midx[mi] = ci;
    mwt[mi] = mw;
  }
}

// ---------------- Kernel G: deformable conv as bf16 MFMA GEMM ----------------
// M=cout (tile 128, 2 mt), N=pixels (tile 64 -> 512 blocks, 2/CU), K=2304.
// Loop: tap-outer (meta in regs, reused over 4 c-chunks), kc=tap*4+cc.
__global__ __launch_bounds__(256) void k_gemm(
    const u16* __restrict__ xt, const u16* __restrict__ warr,
    const int4* __restrict__ midx, const float4* __restrict__ mwt,
    float* __restrict__ out) {
  __shared__ u16 a_t[8 * 1024];  // [g][m=128][kk=8] 16 KB
  __shared__ u16 b_t[8 * 520];   // [g][px=64][kk=8] + 8-u16 pad per g
  int tid = threadIdx.x;
  int lane = tid & 63;
  int wave = tid >> 6;
  int wm = wave & 1, wn = wave >> 1;  // wave tile: 64 m x 32 n
  int mt = blockIdx.y;
  int bx = blockIdx.x;
  int b = bx >> 6, pt = bx & 63;
  int p0 = pt * 64;

  int q = tid & 15;    // channel quad (ch = q*4 within 64-ch chunk)
  int pxb = tid >> 4;  // 0..15

  f32x4_t acc[4][2] = {};

#pragma unroll 1
  for (int tap = 0; tap < 9; tap++) {
    int4 ci[4];
    float4 mw[4];
#pragma unroll
    for (int i = 0; i < 4; i++) {
      int mi = (b * 9 + tap) * HW + p0 + i * 16 + pxb;
      ci[i] = midx[mi];
      mw[i] = mwt[mi];
    }
#pragma unroll 1
    for (int cc = 0; cc < 4; cc++) {
      int kc = tap * 4 + cc;
      // --- A stage: 16KB bf16 chunk (register path) ---
      const uint4* asrc = (const uint4*)(warr + (kc * 2 + mt) * 8192);
#pragma unroll
      for (int i = 0; i < 4; i++) {
        uint4 v = asrc[tid + i * 256];
        *(uint4*)&a_t[(tid + i * 256) * 8] = v;
      }
      // --- B stage: bilinear blend 64px x 64ch (bf16 corners) ---
      int e = cc * 64 + q * 4;
#pragma unroll
      for (int i = 0; i < 4; i++) {
        uint2 c0v = *(const uint2*)&xt[ci[i].x + e];
        uint2 c1v = *(const uint2*)&xt[ci[i].y + e];
        uint2 c2v = *(const uint2*)&xt[ci[i].z + e];
        uint2 c3v = *(const uint2*)&xt[ci[i].w + e];
        float4 m4 = mw[i];
        float r0 = m4.x * bf_lo(c0v.x) + m4.y * bf_lo(c1v.x) + m4.z * bf_lo(c2v.x) + m4.w * bf_lo(c3v.x);
        float r1 = m4.x * bf_hi(c0v.x) + m4.y * bf_hi(c1v.x) + m4.z * bf_hi(c2v.x) + m4.w * bf_hi(c3v.x);
        float r2 = m4.x * bf_lo(c0v.y) + m4.y * bf_lo(c1v.y) + m4.z * bf_lo(c2v.y) + m4.w * bf_lo(c3v.y);
        float r3 = m4.x * bf_hi(c0v.y) + m4.y * bf_hi(c1v.y) + m4.z * bf_hi(c2v.y) + m4.w * bf_hi(c3v.y);
        uint2 u;
        u.x = f32_to_bf16_rne(r0) | (f32_to_bf16_rne(r1) << 16);
        u.y = f32_to_bf16_rne(r2) | (f32_to_bf16_rne(r3) << 16);
        int px = i * 16 + pxb;
        *(uint2*)&b_t[(q >> 1) * 520 + px * 8 + (q & 1) * 4] = u;
      }
      __syncthreads();
#pragma unroll
      for (int ks = 0; ks < 2; ks++) {
        int g = ks * 4 + (lane >> 4);
        bf16x8 af[4], bfr[2];
#pragma unroll
        for (int im = 0; im < 4; im++)
          af[im] = *(bf16x8*)&a_t[g * 1024 + (wm * 64 + im * 16 + (lane & 15)) * 8];
#pragma unroll
        for (int in = 0; in < 2; in++)
          bfr[in] = *(bf16x8*)&b_t[g * 520 + (wn * 32 + in * 16 + (lane & 15)) * 8];
#pragma unroll
        for (int im = 0; im < 4; im++)
#pragma unroll
          for (int in = 0; in < 2; in++)
            acc[im][in] = __builtin_amdgcn_mfma_f32_16x16x32_bf16(af[im], bfr[in], acc[im][in], 0, 0, 0);
      }
      __syncthreads();
    }
  }
  // --- epilogue: D frag col=lane&15 (pixel), row=(lane>>4)*4+r (cout) -> NCHW ---
  int rq = lane >> 4;
#pragma unroll
  for (int im = 0; im < 4; im++) {
#pragma unroll
    for (int in = 0; in < 2; in++) {
      int n = p0 + wn * 32 + in * 16 + (lane & 15);
#pragma unroll
      for (int r = 0; r < 4; r++) {
        int m = mt * 128 + wm * 64 + im * 16 + rq * 4 + r;
        out[(b * 256 + m) * HW + n] = acc[im][in][r];
      }
    }
  }
}

// ---------------- Kernel R: GroupNorm partial sums (per b,group quarter) ----------------
__global__ __launch_bounds__(256) void k_gn_part(const float* __restrict__ out,
                                                 float2* __restrict__ part) {
  int blk = blockIdx.x;           // 512 = 128 bg * 4 quarters
  int bg = blk >> 2, qt = blk & 3;
  const float4* base = (const float4*)(out + (size_t)bg * 32768 + (size_t)qt * 8192);
  int tid = threadIdx.x;
  float s = 0.f, ss = 0.f;
#pragma unroll
  for (int i = 0; i < 8; i++) {
    float4 v = base[tid + i * 256];
    s += v.x + v.y + v.z + v.w;
    ss += v.x * v.x + v.y * v.y + v.z * v.z + v.w * v.w;
  }
#pragma unroll
  for (int m = 1; m < 64; m <<= 1) {
    s += __shfl_xor(s, m);
    ss += __shfl_xor(ss, m);
  }
  __shared__ float ls[4], lss[4];
  int wv = tid >> 6, lane = tid & 63;
  if (lane == 0) { ls[wv] = s; lss[wv] = ss; }
  __syncthreads();
  if (tid == 0)
    part[blk] = make_float2(ls[0] + ls[1] + ls[2] + ls[3],
                            lss[0] + lss[1] + lss[2] + lss[3]);
}

// ---------------- Kernel N: finalize stats + normalize + ReLU in place ----------------
// Block covers 256 float4 within a single (b,c) row -> stats computed once per block.
__global__ __launch_bounds__(256) void k_gn_apply(float* __restrict__ out,
                                                  const float2* __restrict__ part,
                                                  const float* __restrict__ gamma,
                                                  const float* __restrict__ beta) {
  __shared__ float sga, sbe;
  int gid = blockIdx.x * 256 + threadIdx.x;  // float4 index, < 1048576
  int c = (gid >> 10) & 255;
  int bb = gid >> 18;
  if (threadIdx.x == 0) {
    int p4 = (bb * 32 + (c >> 3)) * 4;
    float s = 0.f, ss = 0.f;
#pragma unroll
    for (int j = 0; j < 4; j++) {
      float2 p = part[p4 + j];
      s += p.x;
      ss += p.y;
    }
    float mu = s / 32768.f;
    float var = ss / 32768.f - mu * mu;
    float rs = rsqrtf(var + 1e-5f);
    float ga = gamma[c] * rs;
    sga = ga;
    sbe = beta[c] - mu * ga;
  }
  __syncthreads();
  float ga = sga, be = sbe;
  float4 v = ((const float4*)out)[gid];
  v.x = fmaxf(v.x * ga + be, 0.f);
  v.y = fmaxf(v.y * ga + be, 0.f);
  v.z = fmaxf(v.z * ga + be, 0.f);
  v.w = fmaxf(v.w * ga + be, 0.f);
  ((float4*)out)[gid] = v;
}

extern "C" void kernel_launch(void* const* d_in, const int* in_sizes, int n_in,
                              void* d_out, int out_size, void* d_ws, size_t ws_size,
                              hipStream_t stream) {
  const float* x = (const float*)d_in[0];
  const float* offset_w = (const float*)d_in[1];
  const float* offset_b = (const float*)d_in[2];
  const float* deform_w = (const float*)d_in[3];
  const float* gn_gamma = (const float*)d_in[4];
  const float* gn_beta = (const float*)d_in[5];
  float* out = (float*)d_out;
  char* ws = (char*)d_ws;

  u16* xt = (u16*)ws;                                   //  8,388,608 B (bf16 NHWC)
  int4* midx = (int4*)(ws + 8388608);                   //  2,359,296 B
  float4* mwt = (float4*)(ws + 8388608 + 2359296);      //  2,359,296 B
  u16* warr = (u16*)(ws + 8388608 + 2 * 2359296);       //  1,179,648 B
  float* owt = (float*)(ws + 8388608 + 2 * 2359296 + 1179648);   // 165,888 B
  float2* part = (float2*)(ws + 8388608 + 2 * 2359296 + 1179648 + 165888);  // 4 KB

  k_transpose<<<dim3(128, 8, 4), dim3(32, 8), 0, stream>>>(x, xt);
  k_prep_w<<<dim3(2304), dim3(256), 0, stream>>>(deform_w, warr);
  k_prep_ow<<<dim3(162), dim3(256), 0, stream>>>(offset_w, owt);
  k_offset_meta<<<dim3(4096), dim3(256), 0, stream>>>(xt, owt, offset_b, midx, mwt);
  k_gemm<<<dim3(256, 2), dim3(256), 0, stream>>>(xt, warr, midx, mwt, out);
  k_gn_part<<<dim3(512), dim3(256), 0, stream>>>(out, part);
  k_gn_apply<<<dim3(4096), dim3(256), 0, stream>>>(out, part, gn_gamma, gn_beta);
}

// Round 7
// 258.506 us; speedup vs baseline: 2.3187x; 1.0999x over previous
//
#include <hip/hip_runtime.h>
#include <hip/hip_bf16.h>
#include <stdint.h>

// DeformableBlock: offset-conv -> deformable conv (bf16 MFMA GEMM) -> GroupNorm+ReLU
// B=4, CIN=COUT=256, H=W=64, K=3x3=9 taps, GN groups=32.
// xt in bf16 NHWC. k_gemm: double-buffered LDS, prefetch next chunk's global
// loads before MFMA (hide gather latency). k_offset_meta: 4 px/wave (weight reuse).

typedef unsigned short u16;
typedef __bf16 bf16x8 __attribute__((ext_vector_type(8)));
typedef float f32x4_t __attribute__((ext_vector_type(4)));

#define HW 4096

__device__ __forceinline__ uint32_t f32_to_bf16_rne(float f) {
  uint32_t u = __builtin_bit_cast(uint32_t, f);
  return (u + 0x7FFFu + ((u >> 16) & 1u)) >> 16;
}
__device__ __forceinline__ float bf_lo(uint32_t u) {
  return __builtin_bit_cast(float, u << 16);
}
__device__ __forceinline__ float bf_hi(uint32_t u) {
  return __builtin_bit_cast(float, u & 0xFFFF0000u);
}

// ---------------- Kernel T: x NCHW f32 -> NHWC bf16 ----------------
__global__ __launch_bounds__(256) void k_transpose(const float* __restrict__ x,
                                                   u16* __restrict__ xt) {
  __shared__ float tile[32][33];
  int b = blockIdx.z;
  int c0 = blockIdx.y * 32;
  int p0 = blockIdx.x * 32;
  int tx = threadIdx.x, ty = threadIdx.y;  // 32 x 8
#pragma unroll
  for (int j = 0; j < 32; j += 8)
    tile[ty + j][tx] = x[(b * 256 + c0 + ty + j) * HW + p0 + tx];
  __syncthreads();
  int wid = ty * 32 + tx;
  int cp = wid & 15;
  int pr = wid >> 4;
#pragma unroll
  for (int j = 0; j < 2; j++) {
    int p = pr + j * 16;
    uint32_t lo = f32_to_bf16_rne(tile[cp * 2][p]);
    uint32_t hi = f32_to_bf16_rne(tile[cp * 2 + 1][p]);
    *(uint32_t*)&xt[(b * HW + p0 + p) * 256 + c0 + cp * 2] = lo | (hi << 16);
  }
}

// ---------------- Kernel W1: deform_w -> bf16 A-tile layout ----------------
// warr[kc][mt][g][m][kk], kc=0..35 (tap=kc>>2, cinblk=(kc&3)*64), g=0..7, m=0..127, kk=0..7
__global__ __launch_bounds__(256) void k_prep_w(const float* __restrict__ wsrc,
                                                u16* __restrict__ warr) {
  int e = blockIdx.x * 256 + threadIdx.x;
  int kk = e & 7, m = (e >> 3) & 127, g = (e >> 10) & 7, mt = (e >> 13) & 1, kc = e >> 14;
  int cout = mt * 128 + m;
  int cin = (kc & 3) * 64 + g * 8 + kk;
  int tap = kc >> 2;
  float v = wsrc[cout * 2304 + cin * 9 + tap];
  warr[e] = (u16)f32_to_bf16_rne(v);
}

// ---------------- Kernel W2: offset_w -> owt[k][oc][c] f32 ----------------
__global__ __launch_bounds__(256) void k_prep_ow(const float* __restrict__ ow,
                                                 float* __restrict__ owt) {
  int e = blockIdx.x * 256 + threadIdx.x;  // (k*18+oc)*256 + c
  int c = e & 255;
  int oc = (e >> 8) % 18;
  int k = e / (18 * 256);
  owt[e] = ow[oc * 2304 + c * 9 + k];
}

// ---------------- Kernel A: offset conv + bilinear metadata ----------------
// One wave per 4 consecutive pixels (weight float4 reused 4x). Lane covers 4 ch.
// k-loop rolled; all acc indexing static (spill lesson, rounds 3/4).
__global__ __launch_bounds__(256) void k_offset_meta(
    const u16* __restrict__ xt, const float* __restrict__ owt,
    const float* __restrict__ ob, int4* __restrict__ midx, float4* __restrict__ mwt) {
  int lane = threadIdx.x & 63;
  int w = blockIdx.x * 4 + (threadIdx.x >> 6);  // pixel-group id, 0..4095
  int b = w >> 10;
  int pp = (w & 1023) * 4;  // first pixel of group (same row: 64%4==0)
  int y = pp >> 6, xx0 = pp & 63;
  float acc[4][18];
#pragma unroll
  for (int j = 0; j < 4; j++)
#pragma unroll
    for (int i = 0; i < 18; i++) acc[j][i] = 0.f;
  int cq = lane * 4;
#pragma unroll 1
  for (int k = 0; k < 9; k++) {
    int ky = k / 3, kx = k % 3;
    int yy = y - 1 + ky;
    bool vy = (yy >= 0) && (yy < 64);
    uint2 xv[4];
    float xf[4][4];
#pragma unroll
    for (int j = 0; j < 4; j++) {
      int xx2 = xx0 + j - 1 + kx;
      xv[j] = make_uint2(0u, 0u);
      if (vy && xx2 >= 0 && xx2 < 64)
        xv[j] = *(const uint2*)&xt[(b * HW + yy * 64 + xx2) * 256 + cq];
      xf[j][0] = bf_lo(xv[j].x);
      xf[j][1] = bf_hi(xv[j].x);
      xf[j][2] = bf_lo(xv[j].y);
      xf[j][3] = bf_hi(xv[j].y);
    }
#pragma unroll
    for (int oc = 0; oc < 18; oc++) {
      float4 w4 = *(const float4*)&owt[((k * 18 + oc) << 8) + cq];
#pragma unroll
      for (int j = 0; j < 4; j++)
        acc[j][oc] += xf[j][0] * w4.x + xf[j][1] * w4.y + xf[j][2] * w4.z + xf[j][3] * w4.w;
    }
  }
#pragma unroll
  for (int j = 0; j < 4; j++)
#pragma unroll
    for (int oc = 0; oc < 18; oc++) {
      float v = acc[j][oc];
#pragma unroll
      for (int m = 1; m < 64; m <<= 1) v += __shfl_xor(v, m);
      acc[j][oc] = v;
    }
  // lane = tap*4 + px for lane<36: static select
  float dy = 0.f, dx = 0.f;
#pragma unroll
  for (int t = 0; t < 9; t++)
#pragma unroll
    for (int p_ = 0; p_ < 4; p_++)
      if (lane == t * 4 + p_) { dy = acc[p_][2 * t]; dx = acc[p_][2 * t + 1]; }
  if (lane < 36) {
    int tap = lane >> 2;
    int px = lane & 3;
    int ky = tap / 3, kx = tap % 3;
    dy += ob[2 * tap];
    dx += ob[2 * tap + 1];
    int p = pp + px;
    int yq = p >> 6, xq = p & 63;
    float py = (float)(yq - 1 + ky) + dy;
    float pxx = (float)(xq - 1 + kx) + dx;
    float y0f = floorf(py), x0f = floorf(pxx);
    float ty = py - y0f, tx = pxx - x0f;
    int y0 = (int)y0f, x0 = (int)x0f;
    int y1 = y0 + 1, x1 = x0 + 1;
    float wy0 = 1.f - ty, wy1 = ty, wx0 = 1.f - tx, wx1 = tx;
    bool vy0 = (y0 >= 0) && (y0 < 64), vy1 = (y1 >= 0) && (y1 < 64);
    bool vx0 = (x0 >= 0) && (x0 < 64), vx1 = (x1 >= 0) && (x1 < 64);
    int cy0 = min(max(y0, 0), 63), cy1 = min(max(y1, 0), 63);
    int cx0 = min(max(x0, 0), 63), cx1 = min(max(x1, 0), 63);
    int base = b * HW;
    int4 ci;
    ci.x = (base + cy0 * 64 + cx0) * 256;
    ci.y = (base + cy0 * 64 + cx1) * 256;
    ci.z = (base + cy1 * 64 + cx0) * 256;
    ci.w = (base + cy1 * 64 + cx1) * 256;
    float4 mw;
    mw.x = wy0 * wx0 * ((vy0 && vx0) ? 1.f : 0.f);
    mw.y = wy0 * wx1 * ((vy0 && vx1) ? 1.f : 0.f);
    mw.z = wy1 * wx0 * ((vy1 && vx0) ? 1.f : 0.f);
    mw.w = wy1 * wx1 * ((vy1 && vx1) ? 1.f : 0.f);
    int mi = (b * 9 + tap) * HW + p;
    midx[mi] = ci;
    mwt[mi] = mw;
  }
}

// ---------------- Kernel G: deformable conv as bf16 MFMA GEMM (pipelined) ----------------
// M=cout (tile 128, 2 mt), N=pixels (tile 64), K=2304 (36 chunks of 64).
// Double-buffered LDS, 1 barrier/kc; chunk kc+1's global loads issue before MFMA kc.
__global__ __launch_bounds__(256) void k_gemm(
    const u16* __restrict__ xt, const u16* __restrict__ warr,
    const int4* __restrict__ midx, const float4* __restrict__ mwt,
    float* __restrict__ out) {
  __shared__ u16 a_t[2][8192];  // [buf][g*1024 + m*8 + kk] 16 KB each
  __shared__ u16 b_t[2][4160];  // [buf][g*520 + px*8 + kk] 8.125 KB each
  int tid = threadIdx.x;
  int lane = tid & 63;
  int wave = tid >> 6;
  int wm = wave & 1, wn = wave >> 1;  // wave tile 64m x 32n
  int mt = blockIdx.y;
  int bx = blockIdx.x;
  int b = bx >> 6, pt = bx & 63;
  int p0 = pt * 64;
  int q = tid & 15, pxb = tid >> 4;

  f32x4_t acc[4][2] = {};

  int4 ci[4];
  float4 mw[4];
#pragma unroll
  for (int i = 0; i < 4; i++) {
    int mi = (b * 9 + 0) * HW + p0 + i * 16 + pxb;
    ci[i] = midx[mi];
    mw[i] = mwt[mi];
  }
  // prologue: load + stage chunk 0 into buf 0
  {
    const uint4* asrc = (const uint4*)(warr + (0 * 2 + mt) * 8192);
    uint4 apf[4];
#pragma unroll
    for (int i = 0; i < 4; i++) apf[i] = asrc[tid + i * 256];
    int e = q * 4;
#pragma unroll
    for (int i = 0; i < 4; i++) {
      uint2 c0v = *(const uint2*)&xt[ci[i].x + e];
      uint2 c1v = *(const uint2*)&xt[ci[i].y + e];
      uint2 c2v = *(const uint2*)&xt[ci[i].z + e];
      uint2 c3v = *(const uint2*)&xt[ci[i].w + e];
      float4 m4 = mw[i];
      float r0 = m4.x * bf_lo(c0v.x) + m4.y * bf_lo(c1v.x) + m4.z * bf_lo(c2v.x) + m4.w * bf_lo(c3v.x);
      float r1 = m4.x * bf_hi(c0v.x) + m4.y * bf_hi(c1v.x) + m4.z * bf_hi(c2v.x) + m4.w * bf_hi(c3v.x);
      float r2 = m4.x * bf_lo(c0v.y) + m4.y * bf_lo(c1v.y) + m4.z * bf_lo(c2v.y) + m4.w * bf_lo(c3v.y);
      float r3 = m4.x * bf_hi(c0v.y) + m4.y * bf_hi(c1v.y) + m4.z * bf_hi(c2v.y) + m4.w * bf_hi(c3v.y);
      uint2 u;
      u.x = f32_to_bf16_rne(r0) | (f32_to_bf16_rne(r1) << 16);
      u.y = f32_to_bf16_rne(r2) | (f32_to_bf16_rne(r3) << 16);
      int px = i * 16 + pxb;
      *(uint2*)&b_t[0][(q >> 1) * 520 + px * 8 + (q & 1) * 4] = u;
    }
#pragma unroll
    for (int i = 0; i < 4; i++) *(uint4*)&a_t[0][(tid + i * 256) * 8] = apf[i];
  }
  __syncthreads();

#pragma unroll 1
  for (int kc = 0; kc < 36; kc++) {
    int cur = kc & 1;
    u16* a_cur = a_t[cur];
    u16* b_cur = b_t[cur];
    u16* a_nxt = a_t[cur ^ 1];
    u16* b_nxt = b_t[cur ^ 1];
    bool have = kc < 35;
    uint4 napf[4];
    uint2 ncpf[4][4];
    if (have) {
      int nkc = kc + 1, ntap = nkc >> 2, ncc = nkc & 3;
      if (ncc == 0) {
#pragma unroll
        for (int i = 0; i < 4; i++) {
          int mi = (b * 9 + ntap) * HW + p0 + i * 16 + pxb;
          ci[i] = midx[mi];
          mw[i] = mwt[mi];
        }
      }
      const uint4* asrc = (const uint4*)(warr + (nkc * 2 + mt) * 8192);
#pragma unroll
      for (int i = 0; i < 4; i++) napf[i] = asrc[tid + i * 256];
      int e = ncc * 64 + q * 4;
#pragma unroll
      for (int i = 0; i < 4; i++) {
        ncpf[i][0] = *(const uint2*)&xt[ci[i].x + e];
        ncpf[i][1] = *(const uint2*)&xt[ci[i].y + e];
        ncpf[i][2] = *(const uint2*)&xt[ci[i].z + e];
        ncpf[i][3] = *(const uint2*)&xt[ci[i].w + e];
      }
    }
    // MFMA on current buffer
#pragma unroll
    for (int ks = 0; ks < 2; ks++) {
      int g = ks * 4 + (lane >> 4);
      bf16x8 af[4], bfr[2];
#pragma unroll
      for (int im = 0; im < 4; im++)
        af[im] = *(bf16x8*)&a_cur[g * 1024 + (wm * 64 + im * 16 + (lane & 15)) * 8];
#pragma unroll
      for (int in = 0; in < 2; in++)
        bfr[in] = *(bf16x8*)&b_cur[g * 520 + (wn * 32 + in * 16 + (lane & 15)) * 8];
#pragma unroll
      for (int im = 0; im < 4; im++)
#pragma unroll
        for (int in = 0; in < 2; in++)
          acc[im][in] = __builtin_amdgcn_mfma_f32_16x16x32_bf16(af[im], bfr[in], acc[im][in], 0, 0, 0);
    }
    // stage chunk kc+1 into alternate buffer
    if (have) {
#pragma unroll
      for (int i = 0; i < 4; i++) *(uint4*)&a_nxt[(tid + i * 256) * 8] = napf[i];
#pragma unroll
      for (int i = 0; i < 4; i++) {
        float4 m4 = mw[i];
        float r0 = m4.x * bf_lo(ncpf[i][0].x) + m4.y * bf_lo(ncpf[i][1].x) + m4.z * bf_lo(ncpf[i][2].x) + m4.w * bf_lo(ncpf[i][3].x);
        float r1 = m4.x * bf_hi(ncpf[i][0].x) + m4.y * bf_hi(ncpf[i][1].x) + m4.z * bf_hi(ncpf[i][2].x) + m4.w * bf_hi(ncpf[i][3].x);
        float r2 = m4.x * bf_lo(ncpf[i][0].y) + m4.y * bf_lo(ncpf[i][1].y) + m4.z * bf_lo(ncpf[i][2].y) + m4.w * bf_lo(ncpf[i][3].y);
        float r3 = m4.x * bf_hi(ncpf[i][0].y) + m4.y * bf_hi(ncpf[i][1].y) + m4.z * bf_hi(ncpf[i][2].y) + m4.w * bf_hi(ncpf[i][3].y);
        uint2 u;
        u.x = f32_to_bf16_rne(r0) | (f32_to_bf16_rne(r1) << 16);
        u.y = f32_to_bf16_rne(r2) | (f32_to_bf16_rne(r3) << 16);
        int px = i * 16 + pxb;
        *(uint2*)&b_nxt[(q >> 1) * 520 + px * 8 + (q & 1) * 4] = u;
      }
    }
    __syncthreads();
  }
  // --- epilogue: D frag col=lane&15 (pixel), row=(lane>>4)*4+r (cout) -> NCHW ---
  int rq = lane >> 4;
#pragma unroll
  for (int im = 0; im < 4; im++) {
#pragma unroll
    for (int in = 0; in < 2; in++) {
      int n = p0 + wn * 32 + in * 16 + (lane & 15);
#pragma unroll
      for (int r = 0; r < 4; r++) {
        int m = mt * 128 + wm * 64 + im * 16 + rq * 4 + r;
        out[(b * 256 + m) * HW + n] = acc[im][in][r];
      }
    }
  }
}

// ---------------- Kernel R: GroupNorm partial sums (per b,group quarter) ----------------
__global__ __launch_bounds__(256) void k_gn_part(const float* __restrict__ out,
                                                 float2* __restrict__ part) {
  int blk = blockIdx.x;  // 512 = 128 bg * 4 quarters
  int bg = blk >> 2, qt = blk & 3;
  const float4* base = (const float4*)(out + (size_t)bg * 32768 + (size_t)qt * 8192);
  int tid = threadIdx.x;
  float s = 0.f, ss = 0.f;
#pragma unroll
  for (int i = 0; i < 8; i++) {
    float4 v = base[tid + i * 256];
    s += v.x + v.y + v.z + v.w;
    ss += v.x * v.x + v.y * v.y + v.z * v.z + v.w * v.w;
  }
#pragma unroll
  for (int m = 1; m < 64; m <<= 1) {
    s += __shfl_xor(s, m);
    ss += __shfl_xor(ss, m);
  }
  __shared__ float ls[4], lss[4];
  int wv = tid >> 6, lane = tid & 63;
  if (lane == 0) { ls[wv] = s; lss[wv] = ss; }
  __syncthreads();
  if (tid == 0)
    part[blk] = make_float2(ls[0] + ls[1] + ls[2] + ls[3],
                            lss[0] + lss[1] + lss[2] + lss[3]);
}

// ---------------- Kernel N: finalize stats + normalize + ReLU in place ----------------
__global__ __launch_bounds__(256) void k_gn_apply(float* __restrict__ out,
                                                  const float2* __restrict__ part,
                                                  const float* __restrict__ gamma,
                                                  const float* __restrict__ beta) {
  __shared__ float sga, sbe;
  int gid = blockIdx.x * 256 + threadIdx.x;  // float4 index, < 1048576
  int c = (gid >> 10) & 255;
  int bb = gid >> 18;
  if (threadIdx.x == 0) {
    int p4 = (bb * 32 + (c >> 3)) * 4;
    float s = 0.f, ss = 0.f;
#pragma unroll
    for (int j = 0; j < 4; j++) {
      float2 p = part[p4 + j];
      s += p.x;
      ss += p.y;
    }
    float mu = s / 32768.f;
    float var = ss / 32768.f - mu * mu;
    float rs = rsqrtf(var + 1e-5f);
    float ga = gamma[c] * rs;
    sga = ga;
    sbe = beta[c] - mu * ga;
  }
  __syncthreads();
  float ga = sga, be = sbe;
  float4 v = ((const float4*)out)[gid];
  v.x = fmaxf(v.x * ga + be, 0.f);
  v.y = fmaxf(v.y * ga + be, 0.f);
  v.z = fmaxf(v.z * ga + be, 0.f);
  v.w = fmaxf(v.w * ga + be, 0.f);
  ((float4*)out)[gid] = v;
}

extern "C" void kernel_launch(void* const* d_in, const int* in_sizes, int n_in,
                              void* d_out, int out_size, void* d_ws, size_t ws_size,
                              hipStream_t stream) {
  const float* x = (const float*)d_in[0];
  const float* offset_w = (const float*)d_in[1];
  const float* offset_b = (const float*)d_in[2];
  const float* deform_w = (const float*)d_in[3];
  const float* gn_gamma = (const float*)d_in[4];
  const float* gn_beta = (const float*)d_in[5];
  float* out = (float*)d_out;
  char* ws = (char*)d_ws;

  u16* xt = (u16*)ws;                                   //  8,388,608 B (bf16 NHWC)
  int4* midx = (int4*)(ws + 8388608);                   //  2,359,296 B
  float4* mwt = (float4*)(ws + 8388608 + 2359296);      //  2,359,296 B
  u16* warr = (u16*)(ws + 8388608 + 2 * 2359296);       //  1,179,648 B
  float* owt = (float*)(ws + 8388608 + 2 * 2359296 + 1179648);   // 165,888 B
  float2* part = (float2*)(ws + 8388608 + 2 * 2359296 + 1179648 + 165888);  // 4 KB

  k_transpose<<<dim3(128, 8, 4), dim3(32, 8), 0, stream>>>(x, xt);
  k_prep_w<<<dim3(2304), dim3(256), 0, stream>>>(deform_w, warr);
  k_prep_ow<<<dim3(162), dim3(256), 0, stream>>>(offset_w, owt);
  k_offset_meta<<<dim3(1024), dim3(256), 0, stream>>>(xt, owt, offset_b, midx, mwt);
  k_gemm<<<dim3(256, 2), dim3(256), 0, stream>>>(xt, warr, midx, mwt, out);
  k_gn_part<<<dim3(512), dim3(256), 0, stream>>>(out, part);
  k_gn_apply<<<dim3(4096), dim3(256), 0, stream>>>(out, part, gn_gamma, gn_beta);
}

// Round 8
// 179.960 us; speedup vs baseline: 3.3307x; 1.4365x over previous
//
#include <hip/hip_runtime.h>
#include <hip/hip_bf16.h>
#include <stdint.h>

// DeformableBlock: offset-conv (MFMA) -> deformable conv (bf16 MFMA GEMM) -> GroupNorm+ReLU
// B=4, CIN=COUT=256, H=W=64, K=3x3=9 taps, GN groups=32.
// Round 8: occupancy-first. k_gemm: M=256/N=16 tiles -> 1024 blocks (4/CU, 16 waves/CU),
// A read direct from global (L2-hot), tiny B LDS double-buffer, 1 barrier/chunk.
// Offset conv rewritten as MFMA GEMM with wave-private staging (no barriers in K-loop).

typedef unsigned short u16;
typedef __bf16 bf16x8 __attribute__((ext_vector_type(8)));
typedef float f32x4_t __attribute__((ext_vector_type(4)));

#define HW 4096

__device__ __forceinline__ uint32_t f32_to_bf16_rne(float f) {
  uint32_t u = __builtin_bit_cast(uint32_t, f);
  return (u + 0x7FFFu + ((u >> 16) & 1u)) >> 16;
}
__device__ __forceinline__ float bf_lo(uint32_t u) {
  return __builtin_bit_cast(float, u << 16);
}
__device__ __forceinline__ float bf_hi(uint32_t u) {
  return __builtin_bit_cast(float, u & 0xFFFF0000u);
}

// ---------------- Kernel T: x NCHW f32 -> NHWC bf16 ----------------
__global__ __launch_bounds__(256) void k_transpose(const float* __restrict__ x,
                                                   u16* __restrict__ xt) {
  __shared__ float tile[32][33];
  int b = blockIdx.z;
  int c0 = blockIdx.y * 32;
  int p0 = blockIdx.x * 32;
  int tx = threadIdx.x, ty = threadIdx.y;  // 32 x 8
#pragma unroll
  for (int j = 0; j < 32; j += 8)
    tile[ty + j][tx] = x[(b * 256 + c0 + ty + j) * HW + p0 + tx];
  __syncthreads();
  int wid = ty * 32 + tx;
  int cp = wid & 15;
  int pr = wid >> 4;
#pragma unroll
  for (int j = 0; j < 2; j++) {
    int p = pr + j * 16;
    uint32_t lo = f32_to_bf16_rne(tile[cp * 2][p]);
    uint32_t hi = f32_to_bf16_rne(tile[cp * 2 + 1][p]);
    *(uint32_t*)&xt[(b * HW + p0 + p) * 256 + c0 + cp * 2] = lo | (hi << 16);
  }
}

// ---------------- Kernel W1: deform_w -> bf16 A layout ----------------
// warr[kc 36][g 8][m 256][kk 8]: tap=kc>>2, cin=(kc&3)*64+g*8+kk, cout=m
__global__ __launch_bounds__(256) void k_prep_w(const float* __restrict__ wsrc,
                                                u16* __restrict__ warr) {
  int e = blockIdx.x * 256 + threadIdx.x;  // < 589824
  int kk = e & 7, m = (e >> 3) & 255, g = (e >> 11) & 7, kc = e >> 14;
  int cin = (kc & 3) * 64 + g * 8 + kk;
  int tap = kc >> 2;
  float v = wsrc[m * 2304 + cin * 9 + tap];
  warr[e] = (u16)f32_to_bf16_rne(v);
}

// ---------------- Kernel W2: offset_w -> bf16 A layout (M=32 pad) ----------------
// owm[kc 36][g 8][m 32][kk 8]: m<18 = oc, else 0
__global__ __launch_bounds__(256) void k_prep_owm(const float* __restrict__ ow,
                                                  u16* __restrict__ owm) {
  int e = blockIdx.x * 256 + threadIdx.x;  // < 73728
  int kk = e & 7, m = (e >> 3) & 31, g = (e >> 8) & 7, kc = e >> 11;
  int cin = (kc & 3) * 64 + g * 8 + kk;
  int tap = kc >> 2;
  float v = (m < 18) ? ow[m * 2304 + cin * 9 + tap] : 0.f;
  owm[e] = (u16)f32_to_bf16_rne(v);
}

// ---------------- Kernel O: offset conv (MFMA) + bilinear metadata, fused ----------------
// Block = (b, 16-px tile). 4 waves split the 9 taps (wave w: taps w, w+4, w+8).
// Wave-private B staging in LDS -> ZERO barriers in the K loop. Partial C
// reduced through LDS, then meta computed and midx/mwt written.
__global__ __launch_bounds__(256) void k_offmm(
    const u16* __restrict__ xt, const u16* __restrict__ owm,
    const float* __restrict__ ob, int4* __restrict__ midx, float4* __restrict__ mwt) {
  __shared__ u16 b_w[4][1088];        // per-wave [g8][px16][kk8], stride 136
  __shared__ float off_part[4][16][20];  // per-wave partial C (oc<18)
  int tid = threadIdx.x;
  int lane = tid & 63;
  int w = tid >> 6;
  int b = blockIdx.x >> 8;
  int pt = blockIdx.x & 255;
  int p0 = pt * 16;
  int yrow = p0 >> 6;
  int xbase = p0 & 63;

  f32x4_t acc2[2] = {};
  int q = lane & 15;

#pragma unroll 1
  for (int tap = w; tap < 9; tap += 4) {
    int ky = tap / 3, kx = tap % 3;
    int yy = yrow + ky - 1;
    bool vy = (yy >= 0) && (yy < 64);
#pragma unroll
    for (int cc = 0; cc < 4; cc++) {
      int kc = tap * 4 + cc;
      // stage B slice (16px x 64ch) wave-privately
#pragma unroll
      for (int i = 0; i < 4; i++) {
        int px = i * 4 + (lane >> 4);
        int xx2 = xbase + px + kx - 1;
        uint2 v = make_uint2(0u, 0u);
        if (vy && xx2 >= 0 && xx2 < 64)
          v = *(const uint2*)&xt[(b * HW + yy * 64 + xx2) * 256 + cc * 64 + q * 4];
        *(uint2*)&b_w[w][(q >> 1) * 136 + px * 8 + (q & 1) * 4] = v;
      }
#pragma unroll
      for (int ks = 0; ks < 2; ks++) {
        int g = ks * 4 + (lane >> 4);
        bf16x8 bfr = *(bf16x8*)&b_w[w][g * 136 + (lane & 15) * 8];
#pragma unroll
        for (int im = 0; im < 2; im++) {
          bf16x8 af = *(const bf16x8*)&owm[kc * 2048 + g * 256 + (im * 16 + (lane & 15)) * 8];
          acc2[im] = __builtin_amdgcn_mfma_f32_16x16x32_bf16(af, bfr, acc2[im], 0, 0, 0);
        }
      }
    }
  }
  // write wave-partial C: D col=lane&15 (px), row=(lane>>4)*4+r (oc)
  {
    int px = lane & 15, rq = lane >> 4;
#pragma unroll
    for (int im = 0; im < 2; im++)
#pragma unroll
      for (int r = 0; r < 4; r++) {
        int oc = im * 16 + rq * 4 + r;
        if (oc < 18) off_part[w][px][oc] = acc2[im][r];
      }
  }
  __syncthreads();
  // meta: 144 items = 9 taps x 16 px
  if (tid < 144) {
    int tap = tid >> 4;
    int px = tid & 15;
    float dy = off_part[0][px][2 * tap] + off_part[1][px][2 * tap] +
               off_part[2][px][2 * tap] + off_part[3][px][2 * tap] + ob[2 * tap];
    float dx = off_part[0][px][2 * tap + 1] + off_part[1][px][2 * tap + 1] +
               off_part[2][px][2 * tap + 1] + off_part[3][px][2 * tap + 1] + ob[2 * tap + 1];
    int ky = tap / 3, kx = tap % 3;
    int p = p0 + px;
    int yq = p >> 6, xq = p & 63;
    float py = (float)(yq - 1 + ky) + dy;
    float pxx = (float)(xq - 1 + kx) + dx;
    float y0f = floorf(py), x0f = floorf(pxx);
    float ty = py - y0f, tx = pxx - x0f;
    int y0 = (int)y0f, x0 = (int)x0f;
    int y1 = y0 + 1, x1 = x0 + 1;
    float wy0 = 1.f - ty, wy1 = ty, wx0 = 1.f - tx, wx1 = tx;
    bool vy0 = (y0 >= 0) && (y0 < 64), vy1 = (y1 >= 0) && (y1 < 64);
    bool vx0 = (x0 >= 0) && (x0 < 64), vx1 = (x1 >= 0) && (x1 < 64);
    int cy0 = min(max(y0, 0), 63), cy1 = min(max(y1, 0), 63);
    int cx0 = min(max(x0, 0), 63), cx1 = min(max(x1, 0), 63);
    int base = b * HW;
    int4 ci;
    ci.x = (base + cy0 * 64 + cx0) * 256;
    ci.y = (base + cy0 * 64 + cx1) * 256;
    ci.z = (base + cy1 * 64 + cx0) * 256;
    ci.w = (base + cy1 * 64 + cx1) * 256;
    float4 mw;
    mw.x = wy0 * wx0 * ((vy0 && vx0) ? 1.f : 0.f);
    mw.y = wy0 * wx1 * ((vy0 && vx1) ? 1.f : 0.f);
    mw.z = wy1 * wx0 * ((vy1 && vx0) ? 1.f : 0.f);
    mw.w = wy1 * wx1 * ((vy1 && vx1) ? 1.f : 0.f);
    int mi = (b * 9 + tap) * HW + p;
    midx[mi] = ci;
    mwt[mi] = mw;
  }
}

// ---------------- Kernel G: deformable conv as bf16 MFMA GEMM ----------------
// Block = (b, 16-px tile): M=256, N=16, K=2304. 1024 blocks -> 4/CU, 16 waves/CU.
// Wave wm owns m-strip of 64. A frags loaded direct from global (L2-hot, no A-LDS).
// B (blended samples) in tiny LDS, double-buffered, ONE barrier per chunk.
__global__ __launch_bounds__(256) void k_gemm(
    const u16* __restrict__ xt, const u16* __restrict__ warr,
    const int4* __restrict__ midx, const float4* __restrict__ mwt,
    float* __restrict__ out) {
  __shared__ u16 b_s[2][1088];  // [buf][g8][px16][kk8], stride 136
  int tid = threadIdx.x;
  int lane = tid & 63;
  int wm = tid >> 6;
  int b = blockIdx.x >> 8;
  int pt = blockIdx.x & 255;
  int p0 = pt * 16;
  int q = tid & 15;    // ch-quad within 64-ch chunk
  int pxb = tid >> 4;  // pixel 0..15

  f32x4_t acc4[4] = {};

#pragma unroll 1
  for (int tap = 0; tap < 9; tap++) {
    int mi = (b * 9 + tap) * HW + p0 + pxb;
    int4 ci = midx[mi];
    float4 mw4 = mwt[mi];
#pragma unroll
    for (int cc = 0; cc < 4; cc++) {
      int kc = tap * 4 + cc;
      int e = cc * 64 + q * 4;
      uint2 c0v = *(const uint2*)&xt[ci.x + e];
      uint2 c1v = *(const uint2*)&xt[ci.y + e];
      uint2 c2v = *(const uint2*)&xt[ci.z + e];
      uint2 c3v = *(const uint2*)&xt[ci.w + e];
      float r0 = mw4.x * bf_lo(c0v.x) + mw4.y * bf_lo(c1v.x) + mw4.z * bf_lo(c2v.x) + mw4.w * bf_lo(c3v.x);
      float r1 = mw4.x * bf_hi(c0v.x) + mw4.y * bf_hi(c1v.x) + mw4.z * bf_hi(c2v.x) + mw4.w * bf_hi(c3v.x);
      float r2 = mw4.x * bf_lo(c0v.y) + mw4.y * bf_lo(c1v.y) + mw4.z * bf_lo(c2v.y) + mw4.w * bf_lo(c3v.y);
      float r3 = mw4.x * bf_hi(c0v.y) + mw4.y * bf_hi(c1v.y) + mw4.z * bf_hi(c2v.y) + mw4.w * bf_hi(c3v.y);
      uint2 u;
      u.x = f32_to_bf16_rne(r0) | (f32_to_bf16_rne(r1) << 16);
      u.y = f32_to_bf16_rne(r2) | (f32_to_bf16_rne(r3) << 16);
      *(uint2*)&b_s[kc & 1][(q >> 1) * 136 + pxb * 8 + (q & 1) * 4] = u;
      __syncthreads();
      // MFMA: A direct from global, B from LDS
#pragma unroll
      for (int ks = 0; ks < 2; ks++) {
        int g = ks * 4 + (lane >> 4);
        bf16x8 bfr = *(bf16x8*)&b_s[kc & 1][g * 136 + (lane & 15) * 8];
        const u16* abase = warr + kc * 16384 + g * 2048 + (wm * 64 + (lane & 15)) * 8;
#pragma unroll
        for (int im = 0; im < 4; im++) {
          bf16x8 af = *(const bf16x8*)&abase[im * 128];  // im*16 rows * 8
          acc4[im] = __builtin_amdgcn_mfma_f32_16x16x32_bf16(af, bfr, acc4[im], 0, 0, 0);
        }
      }
      // no trailing barrier: next cc writes the other buffer; the next
      // iteration's barrier orders buffer reuse (2-deep rotation is safe).
    }
  }
  // epilogue: D col=lane&15 (px), row=(lane>>4)*4+r (cout within 16-frag)
  int rq = lane >> 4;
  int n = p0 + (lane & 15);
#pragma unroll
  for (int im = 0; im < 4; im++) {
#pragma unroll
    for (int r = 0; r < 4; r++) {
      int m = wm * 64 + im * 16 + rq * 4 + r;
      out[(b * 256 + m) * HW + n] = acc4[im][r];
    }
  }
}

// ---------------- Kernel R: GroupNorm partial sums (per b,group quarter) ----------------
__global__ __launch_bounds__(256) void k_gn_part(const float* __restrict__ out,
                                                 float2* __restrict__ part) {
  int blk = blockIdx.x;  // 512 = 128 bg * 4 quarters
  int bg = blk >> 2, qt = blk & 3;
  const float4* base = (const float4*)(out + (size_t)bg * 32768 + (size_t)qt * 8192);
  int tid = threadIdx.x;
  float s = 0.f, ss = 0.f;
#pragma unroll
  for (int i = 0; i < 8; i++) {
    float4 v = base[tid + i * 256];
    s += v.x + v.y + v.z + v.w;
    ss += v.x * v.x + v.y * v.y + v.z * v.z + v.w * v.w;
  }
#pragma unroll
  for (int m = 1; m < 64; m <<= 1) {
    s += __shfl_xor(s, m);
    ss += __shfl_xor(ss, m);
  }
  __shared__ float ls[4], lss[4];
  int wv = tid >> 6, lane = tid & 63;
  if (lane == 0) { ls[wv] = s; lss[wv] = ss; }
  __syncthreads();
  if (tid == 0)
    part[blk] = make_float2(ls[0] + ls[1] + ls[2] + ls[3],
                            lss[0] + lss[1] + lss[2] + lss[3]);
}

// ---------------- Kernel N: finalize stats + normalize + ReLU in place ----------------
__global__ __launch_bounds__(256) void k_gn_apply(float* __restrict__ out,
                                                  const float2* __restrict__ part,
                                                  const float* __restrict__ gamma,
                                                  const float* __restrict__ beta) {
  __shared__ float sga, sbe;
  int gid = blockIdx.x * 256 + threadIdx.x;  // float4 index, < 1048576
  int c = (gid >> 10) & 255;
  int bb = gid >> 18;
  if (threadIdx.x == 0) {
    int p4 = (bb * 32 + (c >> 3)) * 4;
    float s = 0.f, ss = 0.f;
#pragma unroll
    for (int j = 0; j < 4; j++) {
      float2 p = part[p4 + j];
      s += p.x;
      ss += p.y;
    }
    float mu = s / 32768.f;
    float var = ss / 32768.f - mu * mu;
    float rs = rsqrtf(var + 1e-5f);
    float ga = gamma[c] * rs;
    sga = ga;
    sbe = beta[c] - mu * ga;
  }
  __syncthreads();
  float ga = sga, be = sbe;
  float4 v = ((const float4*)out)[gid];
  v.x = fmaxf(v.x * ga + be, 0.f);
  v.y = fmaxf(v.y * ga + be, 0.f);
  v.z = fmaxf(v.z * ga + be, 0.f);
  v.w = fmaxf(v.w * ga + be, 0.f);
  ((float4*)out)[gid] = v;
}

extern "C" void kernel_launch(void* const* d_in, const int* in_sizes, int n_in,
                              void* d_out, int out_size, void* d_ws, size_t ws_size,
                              hipStream_t stream) {
  const float* x = (const float*)d_in[0];
  const float* offset_w = (const float*)d_in[1];
  const float* offset_b = (const float*)d_in[2];
  const float* deform_w = (const float*)d_in[3];
  const float* gn_gamma = (const float*)d_in[4];
  const float* gn_beta = (const float*)d_in[5];
  float* out = (float*)d_out;
  char* ws = (char*)d_ws;

  u16* xt = (u16*)ws;                               //  8,388,608 B (bf16 NHWC)
  int4* midx = (int4*)(ws + 8388608);               //  2,359,296 B
  float4* mwt = (float4*)(ws + 10747904);           //  2,359,296 B
  u16* warr = (u16*)(ws + 13107200);                //  1,179,648 B
  u16* owm = (u16*)(ws + 14286848);                 //    147,456 B
  float2* part = (float2*)(ws + 14434304);          //      4,096 B

  k_transpose<<<dim3(128, 8, 4), dim3(32, 8), 0, stream>>>(x, xt);
  k_prep_w<<<dim3(2304), dim3(256), 0, stream>>>(deform_w, warr);
  k_prep_owm<<<dim3(288), dim3(256), 0, stream>>>(offset_w, owm);
  k_offmm<<<dim3(1024), dim3(256), 0, stream>>>(xt, owm, offset_b, midx, mwt);
  k_gemm<<<dim3(1024), dim3(256), 0, stream>>>(xt, warr, midx, mwt, out);
  k_gn_part<<<dim3(512), dim3(256), 0, stream>>>(out, part);
  k_gn_apply<<<dim3(4096), dim3(256), 0, stream>>>(out, part, gn_gamma, gn_beta);
}

// Round 9
// 172.134 us; speedup vs baseline: 3.4822x; 1.0455x over previous
//
#include <hip/hip_runtime.h>
#include <hip/hip_bf16.h>
#include <stdint.h>

// DeformableBlock: fused [offset-conv (MFMA) + meta + deformable conv (MFMA GEMM)]
// -> GroupNorm+ReLU.  B=4, CIN=COUT=256, H=W=64, 3x3, GN groups=32.
// Round 9: k_offmm fused into k_gemm per 32-px tile (meta via LDS, no midx/mwt
// global round-trip); N=32 as 2x16 subtiles sharing A fragments (halves A L2 traffic).

typedef unsigned short u16;
typedef __bf16 bf16x8 __attribute__((ext_vector_type(8)));
typedef float f32x4_t __attribute__((ext_vector_type(4)));

#define HW 4096

__device__ __forceinline__ uint32_t f32_to_bf16_rne(float f) {
  uint32_t u = __builtin_bit_cast(uint32_t, f);
  return (u + 0x7FFFu + ((u >> 16) & 1u)) >> 16;
}
__device__ __forceinline__ float bf_lo(uint32_t u) {
  return __builtin_bit_cast(float, u << 16);
}
__device__ __forceinline__ float bf_hi(uint32_t u) {
  return __builtin_bit_cast(float, u & 0xFFFF0000u);
}

// ---------------- Kernel T: x NCHW f32 -> NHWC bf16 ----------------
__global__ __launch_bounds__(256) void k_transpose(const float* __restrict__ x,
                                                   u16* __restrict__ xt) {
  __shared__ float tile[32][33];
  int b = blockIdx.z;
  int c0 = blockIdx.y * 32;
  int p0 = blockIdx.x * 32;
  int tx = threadIdx.x, ty = threadIdx.y;  // 32 x 8
#pragma unroll
  for (int j = 0; j < 32; j += 8)
    tile[ty + j][tx] = x[(b * 256 + c0 + ty + j) * HW + p0 + tx];
  __syncthreads();
  int wid = ty * 32 + tx;
  int cp = wid & 15;
  int pr = wid >> 4;
#pragma unroll
  for (int j = 0; j < 2; j++) {
    int p = pr + j * 16;
    uint32_t lo = f32_to_bf16_rne(tile[cp * 2][p]);
    uint32_t hi = f32_to_bf16_rne(tile[cp * 2 + 1][p]);
    *(uint32_t*)&xt[(b * HW + p0 + p) * 256 + c0 + cp * 2] = lo | (hi << 16);
  }
}

// ---------------- Kernel W1: deform_w -> bf16 A layout ----------------
// warr[kc 36][g 8][m 256][kk 8]: tap=kc>>2, cin=(kc&3)*64+g*8+kk, cout=m
__global__ __launch_bounds__(256) void k_prep_w(const float* __restrict__ wsrc,
                                                u16* __restrict__ warr) {
  int e = blockIdx.x * 256 + threadIdx.x;  // < 589824
  int kk = e & 7, m = (e >> 3) & 255, g = (e >> 11) & 7, kc = e >> 14;
  int cin = (kc & 3) * 64 + g * 8 + kk;
  int tap = kc >> 2;
  float v = wsrc[m * 2304 + cin * 9 + tap];
  warr[e] = (u16)f32_to_bf16_rne(v);
}

// ---------------- Kernel W2: offset_w -> bf16 A layout (M=32 pad) ----------------
// owm[kc 36][g 8][m 32][kk 8]: m<18 = oc, else 0
__global__ __launch_bounds__(256) void k_prep_owm(const float* __restrict__ ow,
                                                  u16* __restrict__ owm) {
  int e = blockIdx.x * 256 + threadIdx.x;  // < 73728
  int kk = e & 7, m = (e >> 3) & 31, g = (e >> 8) & 7, kc = e >> 11;
  int cin = (kc & 3) * 64 + g * 8 + kk;
  int tap = kc >> 2;
  float v = (m < 18) ? ow[m * 2304 + cin * 9 + tap] : 0.f;
  owm[e] = (u16)f32_to_bf16_rne(v);
}

// ---------------- Kernel C: FUSED offset-conv + meta + deformable GEMM ----------------
// Block = (b, 32-px tile), 512 blocks. Phase A: offset conv M=32,N=32,K=2304
// (4 waves split taps, wave-private LDS staging, zero barriers). Meta -> LDS.
// Phase B: deformable GEMM M=256,N=32 (2x16 subtiles share A frags), B LDS
// double-buffered, one barrier/chunk.
__global__ __launch_bounds__(256) void k_conv(
    const u16* __restrict__ xt, const u16* __restrict__ warr,
    const u16* __restrict__ owm, const float* __restrict__ ob,
    float* __restrict__ out) {
  __shared__ char smem[27136];
  u16* stage = (u16*)smem;                   // phase A: [w4][2112 u16] (16896 B)
  float* off_part = (float*)(smem + 16896);  // phase A: [w4][px32][20]  (10240 B)
  int4* ci_s = (int4*)smem;                  // meta/B:  [288]           (4608 B)
  float4* mw_s = (float4*)(smem + 4608);     // meta/B:  [288]           (4608 B)
  u16* b_s = (u16*)(smem + 16896);           // phase B: [2buf][2sub][1088 u16] (8704 B)

  int tid = threadIdx.x;
  int lane = tid & 63;
  int wm = tid >> 6;
  int b = blockIdx.x >> 7;
  int pt = blockIdx.x & 127;
  int p0 = pt * 32;
  int yrow = p0 >> 6, xbase = p0 & 63;

  // ---- Phase A: offset conv; wave w handles taps w, w+4, w+8 ----
  {
    u16* st = stage + wm * 2112;
    int q = lane & 15, pq = lane >> 4;
    f32x4_t a2[2][2] = {};
#pragma unroll 1
    for (int tap = wm; tap < 9; tap += 4) {
      int ky = tap / 3, kx = tap % 3;
      int yy = yrow + ky - 1;
      bool vy = (yy >= 0) && (yy < 64);
#pragma unroll
      for (int cc = 0; cc < 4; cc++) {
        int kc = tap * 4 + cc;
#pragma unroll
        for (int i = 0; i < 8; i++) {
          int px = i * 4 + pq;
          int xx2 = xbase + px + kx - 1;
          uint2 v = make_uint2(0u, 0u);
          if (vy && xx2 >= 0 && xx2 < 64)
            v = *(const uint2*)&xt[(b * HW + yy * 64 + xx2) * 256 + cc * 64 + q * 4];
          *(uint2*)&st[(q >> 1) * 264 + px * 8 + (q & 1) * 4] = v;
        }
#pragma unroll
        for (int ks = 0; ks < 2; ks++) {
          int g = ks * 4 + pq;
          const u16* ab = owm + kc * 2048 + g * 256;
#pragma unroll
          for (int s = 0; s < 2; s++) {
            bf16x8 bfr = *(bf16x8*)&st[g * 264 + (s * 16 + q) * 8];
#pragma unroll
            for (int im = 0; im < 2; im++) {
              bf16x8 af = *(const bf16x8*)&ab[(im * 16 + q) * 8];
              a2[s][im] = __builtin_amdgcn_mfma_f32_16x16x32_bf16(af, bfr, a2[s][im], 0, 0, 0);
            }
          }
        }
      }
    }
    // D: col = q (px within sub), row = pq*4+r (+im*16) = oc
#pragma unroll
    for (int s = 0; s < 2; s++)
#pragma unroll
      for (int im = 0; im < 2; im++)
#pragma unroll
        for (int r = 0; r < 4; r++) {
          int oc = im * 16 + pq * 4 + r;
          if (oc < 18) off_part[(wm * 32 + s * 16 + q) * 20 + oc] = a2[s][im][r];
        }
  }
  __syncthreads();
  // ---- meta: 288 = 9 taps x 32 px; results to LDS (aliases dead stage) ----
  for (int it = tid; it < 288; it += 256) {
    int tap = it >> 5;
    int px = it & 31;
    float dy = ob[2 * tap], dx = ob[2 * tap + 1];
#pragma unroll
    for (int wv = 0; wv < 4; wv++) {
      dy += off_part[(wv * 32 + px) * 20 + 2 * tap];
      dx += off_part[(wv * 32 + px) * 20 + 2 * tap + 1];
    }
    int ky = tap / 3, kx = tap % 3;
    int p = p0 + px;
    int yq = p >> 6, xq = p & 63;
    float py = (float)(yq - 1 + ky) + dy;
    float pxx = (float)(xq - 1 + kx) + dx;
    float y0f = floorf(py), x0f = floorf(pxx);
    float ty = py - y0f, tx = pxx - x0f;
    int y0 = (int)y0f, x0 = (int)x0f;
    int y1 = y0 + 1, x1 = x0 + 1;
    float wy0 = 1.f - ty, wy1 = ty, wx0 = 1.f - tx, wx1 = tx;
    bool vy0 = (y0 >= 0) && (y0 < 64), vy1 = (y1 >= 0) && (y1 < 64);
    bool vx0 = (x0 >= 0) && (x0 < 64), vx1 = (x1 >= 0) && (x1 < 64);
    int cy0 = min(max(y0, 0), 63), cy1 = min(max(y1, 0), 63);
    int cx0 = min(max(x0, 0), 63), cx1 = min(max(x1, 0), 63);
    int base = b * HW;
    int4 ci;
    ci.x = (base + cy0 * 64 + cx0) * 256;
    ci.y = (base + cy0 * 64 + cx1) * 256;
    ci.z = (base + cy1 * 64 + cx0) * 256;
    ci.w = (base + cy1 * 64 + cx1) * 256;
    float4 mw;
    mw.x = wy0 * wx0 * ((vy0 && vx0) ? 1.f : 0.f);
    mw.y = wy0 * wx1 * ((vy0 && vx1) ? 1.f : 0.f);
    mw.z = wy1 * wx0 * ((vy1 && vx0) ? 1.f : 0.f);
    mw.w = wy1 * wx1 * ((vy1 && vx1) ? 1.f : 0.f);
    ci_s[it] = ci;
    mw_s[it] = mw;
  }
  __syncthreads();

  // ---- Phase B: deformable GEMM M=256, N=32 (2 subtiles share A frags) ----
  int q = tid & 15, pxb = (tid >> 4) & 15;
  f32x4_t acc[2][4] = {};
#pragma unroll 1
  for (int tap = 0; tap < 9; tap++) {
    int4 ci0 = ci_s[tap * 32 + pxb];
    int4 ci1 = ci_s[tap * 32 + 16 + pxb];
    float4 mw0 = mw_s[tap * 32 + pxb];
    float4 mw1 = mw_s[tap * 32 + 16 + pxb];
#pragma unroll
    for (int cc = 0; cc < 4; cc++) {
      int kc = tap * 4 + cc;
      int e = cc * 64 + q * 4;
      u16* bb = b_s + (kc & 1) * 2176;
      {
        uint2 c0v = *(const uint2*)&xt[ci0.x + e];
        uint2 c1v = *(const uint2*)&xt[ci0.y + e];
        uint2 c2v = *(const uint2*)&xt[ci0.z + e];
        uint2 c3v = *(const uint2*)&xt[ci0.w + e];
        float r0 = mw0.x * bf_lo(c0v.x) + mw0.y * bf_lo(c1v.x) + mw0.z * bf_lo(c2v.x) + mw0.w * bf_lo(c3v.x);
        float r1 = mw0.x * bf_hi(c0v.x) + mw0.y * bf_hi(c1v.x) + mw0.z * bf_hi(c2v.x) + mw0.w * bf_hi(c3v.x);
        float r2 = mw0.x * bf_lo(c0v.y) + mw0.y * bf_lo(c1v.y) + mw0.z * bf_lo(c2v.y) + mw0.w * bf_lo(c3v.y);
        float r3 = mw0.x * bf_hi(c0v.y) + mw0.y * bf_hi(c1v.y) + mw0.z * bf_hi(c2v.y) + mw0.w * bf_hi(c3v.y);
        uint2 u;
        u.x = f32_to_bf16_rne(r0) | (f32_to_bf16_rne(r1) << 16);
        u.y = f32_to_bf16_rne(r2) | (f32_to_bf16_rne(r3) << 16);
        *(uint2*)&bb[(q >> 1) * 136 + pxb * 8 + (q & 1) * 4] = u;
      }
      {
        uint2 c0v = *(const uint2*)&xt[ci1.x + e];
        uint2 c1v = *(const uint2*)&xt[ci1.y + e];
        uint2 c2v = *(const uint2*)&xt[ci1.z + e];
        uint2 c3v = *(const uint2*)&xt[ci1.w + e];
        float r0 = mw1.x * bf_lo(c0v.x) + mw1.y * bf_lo(c1v.x) + mw1.z * bf_lo(c2v.x) + mw1.w * bf_lo(c3v.x);
        float r1 = mw1.x * bf_hi(c0v.x) + mw1.y * bf_hi(c1v.x) + mw1.z * bf_hi(c2v.x) + mw1.w * bf_hi(c3v.x);
        float r2 = mw1.x * bf_lo(c0v.y) + mw1.y * bf_lo(c1v.y) + mw1.z * bf_lo(c2v.y) + mw1.w * bf_lo(c3v.y);
        float r3 = mw1.x * bf_hi(c0v.y) + mw1.y * bf_hi(c1v.y) + mw1.z * bf_hi(c2v.y) + mw1.w * bf_hi(c3v.y);
        uint2 u;
        u.x = f32_to_bf16_rne(r0) | (f32_to_bf16_rne(r1) << 16);
        u.y = f32_to_bf16_rne(r2) | (f32_to_bf16_rne(r3) << 16);
        *(uint2*)&bb[1088 + (q >> 1) * 136 + pxb * 8 + (q & 1) * 4] = u;
      }
      __syncthreads();
#pragma unroll
      for (int ks = 0; ks < 2; ks++) {
        int g = ks * 4 + (lane >> 4);
        bf16x8 b0 = *(bf16x8*)&bb[g * 136 + (lane & 15) * 8];
        bf16x8 b1 = *(bf16x8*)&bb[1088 + g * 136 + (lane & 15) * 8];
        const u16* ab = warr + kc * 16384 + g * 2048 + (wm * 64 + (lane & 15)) * 8;
#pragma unroll
        for (int im = 0; im < 4; im++) {
          bf16x8 af = *(const bf16x8*)&ab[im * 128];
          acc[0][im] = __builtin_amdgcn_mfma_f32_16x16x32_bf16(af, b0, acc[0][im], 0, 0, 0);
          acc[1][im] = __builtin_amdgcn_mfma_f32_16x16x32_bf16(af, b1, acc[1][im], 0, 0, 0);
        }
      }
      // no trailing barrier: next cc writes the other buffer (2-deep rotation safe)
    }
  }
  // epilogue: D col=lane&15 (px in sub), row=(lane>>4)*4+r -> NCHW
  int rq = lane >> 4;
#pragma unroll
  for (int s = 0; s < 2; s++) {
    int n = p0 + s * 16 + (lane & 15);
#pragma unroll
    for (int im = 0; im < 4; im++)
#pragma unroll
      for (int r = 0; r < 4; r++) {
        int m = wm * 64 + im * 16 + rq * 4 + r;
        out[(b * 256 + m) * HW + n] = acc[s][im][r];
      }
  }
}

// ---------------- Kernel R: GroupNorm partial sums (per b,group quarter) ----------------
__global__ __launch_bounds__(256) void k_gn_part(const float* __restrict__ out,
                                                 float2* __restrict__ part) {
  int blk = blockIdx.x;  // 512 = 128 bg * 4 quarters
  int bg = blk >> 2, qt = blk & 3;
  const float4* base = (const float4*)(out + (size_t)bg * 32768 + (size_t)qt * 8192);
  int tid = threadIdx.x;
  float s = 0.f, ss = 0.f;
#pragma unroll
  for (int i = 0; i < 8; i++) {
    float4 v = base[tid + i * 256];
    s += v.x + v.y + v.z + v.w;
    ss += v.x * v.x + v.y * v.y + v.z * v.z + v.w * v.w;
  }
#pragma unroll
  for (int m = 1; m < 64; m <<= 1) {
    s += __shfl_xor(s, m);
    ss += __shfl_xor(ss, m);
  }
  __shared__ float ls[4], lss[4];
  int wv = tid >> 6, lane = tid & 63;
  if (lane == 0) { ls[wv] = s; lss[wv] = ss; }
  __syncthreads();
  if (tid == 0)
    part[blk] = make_float2(ls[0] + ls[1] + ls[2] + ls[3],
                            lss[0] + lss[1] + lss[2] + lss[3]);
}

// ---------------- Kernel N: finalize stats + normalize + ReLU in place ----------------
__global__ __launch_bounds__(256) void k_gn_apply(float* __restrict__ out,
                                                  const float2* __restrict__ part,
                                                  const float* __restrict__ gamma,
                                                  const float* __restrict__ beta) {
  __shared__ float sga, sbe;
  int gid = blockIdx.x * 256 + threadIdx.x;  // float4 index, < 1048576
  int c = (gid >> 10) & 255;
  int bb = gid >> 18;
  if (threadIdx.x == 0) {
    int p4 = (bb * 32 + (c >> 3)) * 4;
    float s = 0.f, ss = 0.f;
#pragma unroll
    for (int j = 0; j < 4; j++) {
      float2 p = part[p4 + j];
      s += p.x;
      ss += p.y;
    }
    float mu = s / 32768.f;
    float var = ss / 32768.f - mu * mu;
    float rs = rsqrtf(var + 1e-5f);
    float ga = gamma[c] * rs;
    sga = ga;
    sbe = beta[c] - mu * ga;
  }
  __syncthreads();
  float ga = sga, be = sbe;
  float4 v = ((const float4*)out)[gid];
  v.x = fmaxf(v.x * ga + be, 0.f);
  v.y = fmaxf(v.y * ga + be, 0.f);
  v.z = fmaxf(v.z * ga + be, 0.f);
  v.w = fmaxf(v.w * ga + be, 0.f);
  ((float4*)out)[gid] = v;
}

extern "C" void kernel_launch(void* const* d_in, const int* in_sizes, int n_in,
                              void* d_out, int out_size, void* d_ws, size_t ws_size,
                              hipStream_t stream) {
  const float* x = (const float*)d_in[0];
  const float* offset_w = (const float*)d_in[1];
  const float* offset_b = (const float*)d_in[2];
  const float* deform_w = (const float*)d_in[3];
  const float* gn_gamma = (const float*)d_in[4];
  const float* gn_beta = (const float*)d_in[5];
  float* out = (float*)d_out;
  char* ws = (char*)d_ws;

  u16* xt = (u16*)ws;                        //  8,388,608 B (bf16 NHWC)
  u16* warr = (u16*)(ws + 8388608);          //  1,179,648 B
  u16* owm = (u16*)(ws + 9568256);           //    147,456 B
  float2* part = (float2*)(ws + 9715712);    //      4,096 B

  k_transpose<<<dim3(128, 8, 4), dim3(32, 8), 0, stream>>>(x, xt);
  k_prep_w<<<dim3(2304), dim3(256), 0, stream>>>(deform_w, warr);
  k_prep_owm<<<dim3(288), dim3(256), 0, stream>>>(offset_w, owm);
  k_conv<<<dim3(512), dim3(256), 0, stream>>>(xt, warr, owm, offset_b, out);
  k_gn_part<<<dim3(512), dim3(256), 0, stream>>>(out, part);
  k_gn_apply<<<dim3(4096), dim3(256), 0, stream>>>(out, part, gn_gamma, gn_beta);
}